// Round 15
// baseline (357.425 us; speedup 1.0000x reference)
//
#include <hip/hip_runtime.h>

#define S_LEN 2048
#define HID_DIM 4096
#define NH 32
#define NKV 8
#define HD 128
#define QKV_N 6144
#define SCALE_F 0.08838834764831845f

typedef unsigned short u16;
typedef __attribute__((ext_vector_type(8))) __bf16 bf16x8;
typedef __attribute__((ext_vector_type(4))) float f32x4;

__device__ __forceinline__ u16 f2bf(float f) {
  unsigned u = __float_as_uint(f);
  return (u16)((u + 0x7fffu + ((u >> 16) & 1u)) >> 16);
}
__device__ __forceinline__ float bf2f(u16 v) {
  return __uint_as_float((unsigned)v << 16);
}

__device__ __forceinline__ void gl_lds16(const u16* g, u16* l) {
  __builtin_amdgcn_global_load_lds(
      (const __attribute__((address_space(1))) unsigned int*)g,
      (__attribute__((address_space(3))) unsigned int*)l, 16, 0, 0);
}

// ---------------- layout / prep kernels ----------------

__device__ __forceinline__ void tr64_body(const float* __restrict__ A, u16* __restrict__ O,
                                          int ld_in, int ld_out, int r0, int c0, int tid) {
  __shared__ float tile[64][65];
  int tx = tid & 31, ty = tid >> 5;
#pragma unroll
  for (int i = 0; i < 8; i++) {
    int r = ty + 8 * i;
    float2 v = *(const float2*)&A[(long)(r0 + r) * ld_in + c0 + 2 * tx];
    tile[r][2 * tx] = v.x;
    tile[r][2 * tx + 1] = v.y;
  }
  __syncthreads();
#pragma unroll
  for (int i = 0; i < 8; i++) {
    int c = ty + 8 * i;
    ushort2 o;
    o.x = f2bf(tile[2 * tx][c]);
    o.y = f2bf(tile[2 * tx + 1][c]);
    *(ushort2*)&O[(long)(c0 + c) * ld_out + r0 + 2 * tx] = o;
  }
}

__device__ __forceinline__ void tr64u_body(const u16* __restrict__ A, u16* __restrict__ O,
                                           int ld_in, int ld_out, int r0, int c0, int tid) {
  __shared__ u16 tileu[64][66];
  int tx = tid & 31, ty = tid >> 5;
#pragma unroll
  for (int i = 0; i < 8; i++) {
    int r = ty + 8 * i;
    ushort2 v = *(const ushort2*)&A[(long)(r0 + r) * ld_in + c0 + 2 * tx];
    tileu[r][2 * tx] = v.x;
    tileu[r][2 * tx + 1] = v.y;
  }
  __syncthreads();
#pragma unroll
  for (int i = 0; i < 8; i++) {
    int c = ty + 8 * i;
    ushort2 o;
    o.x = tileu[2 * tx][c];
    o.y = tileu[2 * tx + 1][c];
    *(ushort2*)&O[(long)(c0 + c) * ld_out + r0 + 2 * tx] = o;
  }
}

__global__ void k_tr64(const float* __restrict__ in, u16* __restrict__ out,
                       int ld_in, int ld_out, long in_bs, long out_bs) {
  tr64_body(in + (long)blockIdx.z * in_bs, out + (long)blockIdx.z * out_bs,
            ld_in, ld_out, blockIdx.y * 64, blockIdx.x * 64, threadIdx.x);
}

// merged: wq/wk/wv transposes (bid<6144) + hs f32->bf16 (bid>=6144)
__global__ void k_prep(const float* __restrict__ hs, u16* __restrict__ hsb,
                       const float* __restrict__ wq, const float* __restrict__ wk,
                       const float* __restrict__ wv, u16* __restrict__ wT6) {
  int bid = blockIdx.x;
  if (bid < 6144) {
    const float* src; int ld, bx, by; long ooff;
    if (bid < 4096) { src = wq; ld = 4096; ooff = 0; bx = bid & 63; by = bid >> 6; }
    else if (bid < 5120) { int b = bid - 4096; src = wk; ld = 1024; ooff = (long)4096 * HID_DIM; bx = b & 15; by = b >> 4; }
    else { int b = bid - 5120; src = wv; ld = 1024; ooff = (long)5120 * HID_DIM; bx = b & 15; by = b >> 4; }
    tr64_body(src, wT6 + ooff, ld, HID_DIM, by * 64, bx * 64, threadIdx.x);
  } else {
    long i = (long)(bid - 6144) * 256 + threadIdx.x;
    float4 v = ((const float4*)hs)[i];
    ushort4 o;
    o.x = f2bf(v.x); o.y = f2bf(v.y); o.z = f2bf(v.z); o.w = f2bf(v.w);
    ((ushort4*)hsb)[i] = o;
  }
}

// merged: V^T per kv head (bid<512) + mem^T (512..543) + norm copy (544..1055)
__global__ void k_mid(const u16* __restrict__ qkvb, u16* __restrict__ vtb,
                      const float* __restrict__ memf, const float* __restrict__ norm,
                      u16* __restrict__ bc) {
  int bid = blockIdx.x;
  if (bid < 512) {
    int z = bid >> 6, sub = bid & 63;
    int bx = sub & 1, by = sub >> 1;
    tr64u_body(qkvb + HID_DIM + NKV * HD + z * HD, vtb + (long)z * HD * S_LEN,
               QKV_N, S_LEN, by * 64, bx * 64, threadIdx.x);
  } else if (bid < 544) {
    int b = bid - 512;
    int h = b >> 2, sub = b & 3;
    tr64_body(memf + (long)h * HD * HD, bc + (long)h * 32768,
              HD, HD, (sub >> 1) * 64, (sub & 1) * 64, threadIdx.x);
  } else {
    int cid = bid - 544;
    int h = cid >> 6, chunk = cid & 63;
    int i = chunk * 256 + threadIdx.x;
    bc[(long)h * 32768 + 16384 + i] = f2bf(norm[(long)h * 16384 + i]);
  }
}

// ---------------- GEMM v9: 8-phase 256xBN, BK=64, A depth ATRI ----------------
// A rotates over ATRI buffers (16K u16 each at a*16384); B double-buffered at
// ABYTES + d*BN*64. A for tile u staged AHEAD=ATRI-1 tiles before use ->
// HBM-latency cover ~= AHEAD*4 phases. Counted wait WAITN = NBG + 4*(AHEAD-1)
// at ph3/ph7 (ledger: issue order per iter = A(2t+AHEAD)[4], B(2t+2)[NBG],
// A(2t+1+AHEAD)[4], B(2t+3)[NBG]; at ph3-end the newest WAITN ops are exactly
// the stages not needed until later). ATRI=2 reproduces the round-7-proven
// schedule bit-for-bit. Overwrite safety: stage into buffer (u+AHEAD)%ATRI
// happens >= 2 barriers after that buffer's last read (tile u+AHEAD-ATRI).

template <int BN, int ATRI>
__global__ __launch_bounds__(512, 2) void k_gemm8(
    const u16* __restrict__ A, const u16* __restrict__ A2, int zsplit,
    const u16* __restrict__ Bt, void* __restrict__ Cv,
    int kloop, int lda, int ldb, int ldc,
    long strideA, long strideB, long strideC, int bmodB, int obf) {
  constexpr int NBG = BN / 64;
  constexpr int NNI = BN / 64;
  constexpr int AHEAD = ATRI - 1;
  constexpr int WAITN = NBG + 4 * (AHEAD - 1);
  constexpr int AELT = 16384;           // u16 per A buffer
  constexpr int ABYTES = ATRI * AELT;   // u16 offset of B region
  constexpr int BN64 = BN * 64;
  __shared__ __align__(16) u16 lds[ABYTES + 2 * BN64];
  const int bz = blockIdx.z;
  const u16* Ap = (bz < zsplit) ? (A + (long)bz * strideA)
                                : (A2 + (long)(bz - zsplit) * strideA);
  const u16* Bp = Bt + (long)(bz % bmodB) * strideB;
  const long coff = (long)bz * strideC;

  const int gx = gridDim.x, gy = gridDim.y;
  const int nwg = gx * gy;
  int id = blockIdx.y * gx + blockIdx.x;
  if (!(nwg & 7)) { int q = nwg >> 3; id = (id & 7) * q + (id >> 3); }
  const int m0 = (id % gy) * 256;
  const int n0 = (id / gy) * BN;

  const int tid = threadIdx.x, wid = tid >> 6, lane = tid & 63;
  const int l15 = lane & 15, lhi = lane >> 4;
  const int wm = wid >> 2, wn = wid & 3;

  const int srow = (wid << 3) + (lane >> 3);
  const int ssw = ((lane & 7) ^ (lane >> 3)) * 8;
  auto stA = [&](int ab, int g, long kt) {
    gl_lds16(Ap + (long)(m0 + g * 64 + srow) * lda + kt + ssw,
             &lds[ab * AELT + (g * 64 + (wid << 3)) * 64]);
  };
  auto stB = [&](int d, int g, long kt) {
    gl_lds16(Bp + (long)(n0 + g * 64 + srow) * ldb + kt + ssw,
             &lds[ABYTES + d * BN64 + (g * 64 + (wid << 3)) * 64]);
  };

  const int swb = l15 & 7;
  const int aBase = (wm * 128 + l15) * 64;
  const int bBase = (wn * (BN / 4) + l15) * 64;
  const int ko0 = (lhi ^ swb) * 8;
  const int ko1 = ((4 + lhi) ^ swb) * 8;

  const int KT = kloop >> 6;
  const int NIT = KT >> 1;

  f32x4 acc[8][NNI];
#pragma unroll
  for (int i = 0; i < 8; i++)
#pragma unroll
    for (int j = 0; j < NNI; j++) acc[i][j] = (f32x4){0.f, 0.f, 0.f, 0.f};

  // prologue: A0, B0, [A1 if ATRI==3], B1 — ledger-consistent order
#pragma unroll
  for (int g = 0; g < 4; g++) stA(0, g, 0);
#pragma unroll
  for (int g = 0; g < NBG; g++) stB(0, g, 0);
  if (ATRI > 2) {
#pragma unroll
    for (int g = 0; g < 4; g++) stA(1, g, 64);
  }
#pragma unroll
  for (int g = 0; g < NBG; g++) stB(1, g, 64);
  asm volatile("s_waitcnt vmcnt(%0)" :: "i"(WAITN) : "memory");
  __builtin_amdgcn_s_barrier();
  asm volatile("" ::: "memory");

  int ab0 = 0;  // A buffer of tile 2t
  for (int t = 0; t < NIT; ++t) {
    const int uS0 = 2 * t + AHEAD;        // A stage tile, first half
    const int uS1 = 2 * t + 1 + AHEAD;    // A stage tile, second half
    const int abR0 = ab0;
    const int abR1 = (ab0 + 1 < ATRI) ? (ab0 + 1) : 0;
    const int abS0 = (ab0 + AHEAD < ATRI) ? (ab0 + AHEAD) : (ab0 + AHEAD - ATRI);
    const int abS1 = (abS0 + 1 < ATRI) ? (abS0 + 1) : 0;
    const long kA0 = (long)uS0 * 64, kA1 = (long)uS1 * 64;
    const long kB0 = (long)(2 * t + 2) * 64;
    const long kB1 = (long)(2 * t + 3) * 64;
    const bool sA0 = uS0 < KT, sA1 = uS1 < KT;
    const bool sB0 = (2 * t + 2) < KT, sB1 = (2 * t + 3) < KT;
    const bool last = (t + 1 == NIT);

    // ---- phases 0-3: compute tile 2t (A buf abR0, B dbuf 0) ----
    {
      const u16* la = &lds[abR0 * AELT];
      const u16* lbB = &lds[ABYTES];
      bf16x8 Bf[NNI][2];
#pragma unroll
      for (int p = 0; p < 4; p++) {
        if (p == 0) {
#pragma unroll
          for (int ni = 0; ni < NNI; ni++) {
            Bf[ni][0] = *(const bf16x8*)&lbB[bBase + ni * 1024 + ko0];
            Bf[ni][1] = *(const bf16x8*)&lbB[bBase + ni * 1024 + ko1];
          }
        }
        bf16x8 a0k0 = *(const bf16x8*)&la[aBase + (2 * p) * 1024 + ko0];
        bf16x8 a0k1 = *(const bf16x8*)&la[aBase + (2 * p) * 1024 + ko1];
        bf16x8 a1k0 = *(const bf16x8*)&la[aBase + (2 * p + 1) * 1024 + ko0];
        bf16x8 a1k1 = *(const bf16x8*)&la[aBase + (2 * p + 1) * 1024 + ko1];
        if (p == 0) { if (sA0) { stA(abS0, 0, kA0); stA(abS0, 1, kA0); } }
        else if (p == 1) { if (sA0) { stA(abS0, 2, kA0); stA(abS0, 3, kA0); } }
        else if (p == 2) { if (sB0) { stB(0, 0, kB0); stB(0, 1, kB0); } }
        else {
          if (sB0) { stB(0, 2, kB0); if (NBG > 3) stB(0, 3, kB0); }
        }
        asm volatile("" ::: "memory");
        if (p == 3) {
          if (last) asm volatile("s_waitcnt vmcnt(0)" ::: "memory");
          else      asm volatile("s_waitcnt vmcnt(%0)" :: "i"(WAITN) : "memory");
        }
        __builtin_amdgcn_s_barrier();
        asm volatile("" ::: "memory");
        __builtin_amdgcn_s_setprio(1);
#pragma unroll
        for (int ni = 0; ni < NNI; ni++) {
          acc[2 * p][ni] = __builtin_amdgcn_mfma_f32_16x16x32_bf16(a0k0, Bf[ni][0], acc[2 * p][ni], 0, 0, 0);
          acc[2 * p][ni] = __builtin_amdgcn_mfma_f32_16x16x32_bf16(a0k1, Bf[ni][1], acc[2 * p][ni], 0, 0, 0);
          acc[2 * p + 1][ni] = __builtin_amdgcn_mfma_f32_16x16x32_bf16(a1k0, Bf[ni][0], acc[2 * p + 1][ni], 0, 0, 0);
          acc[2 * p + 1][ni] = __builtin_amdgcn_mfma_f32_16x16x32_bf16(a1k1, Bf[ni][1], acc[2 * p + 1][ni], 0, 0, 0);
        }
        __builtin_amdgcn_s_setprio(0);
        asm volatile("" ::: "memory");
        __builtin_amdgcn_s_barrier();
        asm volatile("" ::: "memory");
      }
    }
    // ---- phases 4-7: compute tile 2t+1 (A buf abR1, B dbuf 1) ----
    {
      const u16* la = &lds[abR1 * AELT];
      const u16* lbB = &lds[ABYTES + BN64];
      bf16x8 Bf[NNI][2];
#pragma unroll
      for (int p = 0; p < 4; p++) {
        if (p == 0) {
#pragma unroll
          for (int ni = 0; ni < NNI; ni++) {
            Bf[ni][0] = *(const bf16x8*)&lbB[bBase + ni * 1024 + ko0];
            Bf[ni][1] = *(const bf16x8*)&lbB[bBase + ni * 1024 + ko1];
          }
        }
        bf16x8 a0k0 = *(const bf16x8*)&la[aBase + (2 * p) * 1024 + ko0];
        bf16x8 a0k1 = *(const bf16x8*)&la[aBase + (2 * p) * 1024 + ko1];
        bf16x8 a1k0 = *(const bf16x8*)&la[aBase + (2 * p + 1) * 1024 + ko0];
        bf16x8 a1k1 = *(const bf16x8*)&la[aBase + (2 * p + 1) * 1024 + ko1];
        if (p == 0) { if (sA1) { stA(abS1, 0, kA1); stA(abS1, 1, kA1); } }
        else if (p == 1) { if (sA1) { stA(abS1, 2, kA1); stA(abS1, 3, kA1); } }
        else if (p == 2) { if (sB1) { stB(1, 0, kB1); stB(1, 1, kB1); } }
        else {
          if (sB1) { stB(1, 2, kB1); if (NBG > 3) stB(1, 3, kB1); }
        }
        asm volatile("" ::: "memory");
        if (p == 3 && !last)
          asm volatile("s_waitcnt vmcnt(%0)" :: "i"(WAITN) : "memory");
        __builtin_amdgcn_s_barrier();
        asm volatile("" ::: "memory");
        __builtin_amdgcn_s_setprio(1);
#pragma unroll
        for (int ni = 0; ni < NNI; ni++) {
          acc[2 * p][ni] = __builtin_amdgcn_mfma_f32_16x16x32_bf16(a0k0, Bf[ni][0], acc[2 * p][ni], 0, 0, 0);
          acc[2 * p][ni] = __builtin_amdgcn_mfma_f32_16x16x32_bf16(a0k1, Bf[ni][1], acc[2 * p][ni], 0, 0, 0);
          acc[2 * p + 1][ni] = __builtin_amdgcn_mfma_f32_16x16x32_bf16(a1k0, Bf[ni][0], acc[2 * p + 1][ni], 0, 0, 0);
          acc[2 * p + 1][ni] = __builtin_amdgcn_mfma_f32_16x16x32_bf16(a1k1, Bf[ni][1], acc[2 * p + 1][ni], 0, 0, 0);
        }
        __builtin_amdgcn_s_setprio(0);
        asm volatile("" ::: "memory");
        __builtin_amdgcn_s_barrier();
        asm volatile("" ::: "memory");
      }
    }
    ab0 = (ab0 + 2 < ATRI) ? (ab0 + 2) : (ab0 + 2 - ATRI);
  }

#pragma unroll
  for (int mi = 0; mi < 8; mi++)
#pragma unroll
    for (int ni = 0; ni < NNI; ni++)
#pragma unroll
      for (int j = 0; j < 4; j++) {
        long row = m0 + wm * 128 + mi * 16 + lhi * 4 + j;
        long col = n0 + wn * (BN / 4) + ni * 16 + l15;
        if (obf)
          ((u16*)Cv)[coff + row * ldc + col] = f2bf(acc[mi][ni][j]);
        else
          ((float*)Cv)[coff + row * ldc + col] = acc[mi][ni][j];
      }
}

// ---------------- split-K add epilogue ----------------

__global__ void k_addp(const u16* __restrict__ p0, const u16* __restrict__ p1,
                       float* __restrict__ out) {
  long i = ((long)blockIdx.x * 256 + threadIdx.x) * 8;
  ushort4 a0 = *(const ushort4*)&p0[i], a1 = *(const ushort4*)&p0[i + 4];
  ushort4 b0 = *(const ushort4*)&p1[i], b1 = *(const ushort4*)&p1[i + 4];
  float4 o0, o1;
  o0.x = bf2f(a0.x) + bf2f(b0.x); o0.y = bf2f(a0.y) + bf2f(b0.y);
  o0.z = bf2f(a0.z) + bf2f(b0.z); o0.w = bf2f(a0.w) + bf2f(b0.w);
  o1.x = bf2f(a1.x) + bf2f(b1.x); o1.y = bf2f(a1.y) + bf2f(b1.y);
  o1.z = bf2f(a1.z) + bf2f(b1.z); o1.w = bf2f(a1.w) + bf2f(b1.w);
  *(float4*)&out[i] = o0;
  *(float4*)&out[i + 4] = o1;
}

// ---------------- fused qn + rope (bf16 qkv input) ----------------

__global__ void k_qnrope(const u16* __restrict__ qkv, const int* __restrict__ pos,
                         u16* __restrict__ qnb, u16* __restrict__ qrb,
                         u16* __restrict__ knb, u16* __restrict__ krb) {
  int s = blockIdx.x, y = blockIdx.y, l = threadIdx.x;  // 64 threads
  bool isq = y < NH;
  int h = isq ? y : y - NH;
  const u16* row = qkv + (long)s * QKV_N + (isq ? h * HD : HID_DIM + h * HD);
  float x0 = bf2f(row[l]), x1 = bf2f(row[l + 64]);
  float f0 = x0 > 0.f ? x0 + 1.f : __expf(x0);
  float f1 = x1 > 0.f ? x1 + 1.f : __expf(x1);
  float sum = f0 + f1;
#pragma unroll
  for (int m = 32; m >= 1; m >>= 1) sum += __shfl_xor(sum, m);
  float inv = 1.f / (sum + 1e-8f);
  float y0 = f0 * inv, y1 = f1 * inv;
  long o = ((long)h * S_LEN + s) * HD;
  float p = (float)pos[s];
  float ang = p * expf(-(float)l * (9.210340371976184f / 64.0f));
  float c = cosf(ang), sn = sinf(ang);
  u16 r0 = f2bf(x0 * c - x1 * sn), r1 = f2bf(x1 * c + x0 * sn);
  if (isq) {
    qnb[o + l] = f2bf(y0); qnb[o + l + 64] = f2bf(y1);
    qrb[o + l] = r0; qrb[o + l + 64] = r1;
  } else {
    knb[o + l] = f2bf(y0); knb[o + l + 64] = f2bf(y1);
    krb[o + l] = r0; krb[o + l + 64] = r1;
  }
}

// ---------------- flash attention v4: fused combine epilogue ----------------

__global__ __launch_bounds__(256, 2) void k_flash4(
    const u16* __restrict__ qr, const u16* __restrict__ kr,
    const u16* __restrict__ vt, const u16* __restrict__ rawq,
    const float* __restrict__ beta, u16* __restrict__ comb) {
  __shared__ u16 KV[2][16384];
  __shared__ u16 Ps[4][16 * 64];
  const int bx = blockIdx.x, h = blockIdx.y;
  const int hk = h >> 2;
  const int tid = threadIdx.x, wid = tid >> 6, lane = tid & 63;
  const int l15 = lane & 15, lhi = lane >> 4;
  const u16* qbase = qr + (long)h * S_LEN * HD;
  const u16* kb0 = kr + (long)hk * S_LEN * HD;
  const u16* vb0 = vt + (long)hk * HD * S_LEN;
  u16* P = Ps[wid];
  const float g = 1.f / (1.f + __expf(-beta[0]));

  int kr_r[4], kr_sc[4], vr_r[4], vr_sc[4];
#pragma unroll
  for (int it = 0; it < 4; it++) {
    int chunk = it * 4 + wid;
    kr_r[it] = chunk * 4 + (lane >> 4);
    kr_sc[it] = ((lane & 15) * 8) ^ ((kr_r[it] & 7) * 8);
    vr_r[it] = chunk * 8 + (lane >> 3);
    vr_sc[it] = ((lane & 7) * 8) ^ ((vr_r[it] & 7) * 8);
  }

  for (int si = 0; si < 2; si++) {
    const int s = si ? (31 - bx) : bx;
    const int qs = s * 64 + wid * 16;
    bf16x8 aq[4];
#pragma unroll
    for (int kc = 0; kc < 4; kc++)
      aq[kc] = *(const bf16x8*)&qbase[(long)(qs + l15) * HD + kc * 32 + lhi * 8];
    f32x4 accO[8];
#pragma unroll
    for (int i = 0; i < 8; i++) accO[i] = (f32x4){0.f, 0.f, 0.f, 0.f};
    float rs[4] = {0.f, 0.f, 0.f, 0.f};

    if (si) __syncthreads();
    {
      u16* Kb = KV[0];
#pragma unroll
      for (int it = 0; it < 4; it++)
        gl_lds16(kb0 + (long)kr_r[it] * HD + kr_sc[it], &Kb[(it * 4 + wid) * 512]);
#pragma unroll
      for (int it = 0; it < 4; it++)
        gl_lds16(vb0 + (long)vr_r[it] * S_LEN + vr_sc[it], &Kb[8192 + (it * 4 + wid) * 512]);
    }
    int cur = 0;

    for (int t = 0; t <= s; t++) {
      asm volatile("s_waitcnt vmcnt(0)" ::: "memory");
      __syncthreads();
      if (t < s) {
        u16* Kb = KV[cur ^ 1];
        const long kt = (long)(t + 1) * 64;
#pragma unroll
        for (int it = 0; it < 4; it++)
          gl_lds16(kb0 + (kt + kr_r[it]) * HD + kr_sc[it], &Kb[(it * 4 + wid) * 512]);
#pragma unroll
        for (int it = 0; it < 4; it++)
          gl_lds16(vb0 + (long)vr_r[it] * S_LEN + kt + vr_sc[it], &Kb[8192 + (it * 4 + wid) * 512]);
      }
      const u16* Ks = KV[cur];
      const u16* Vs = Ks + 8192;

      f32x4 accS[4];
#pragma unroll
      for (int i = 0; i < 4; i++) accS[i] = (f32x4){0.f, 0.f, 0.f, 0.f};
#pragma unroll
      for (int ni = 0; ni < 4; ni++) {
        int row = ni * 16 + l15;
#pragma unroll
        for (int kc = 0; kc < 4; kc++) {
          bf16x8 bk = *(const bf16x8*)&Ks[row * 128 + ((kc * 32 + lhi * 8) ^ ((row & 7) * 8))];
          accS[ni] = __builtin_amdgcn_mfma_f32_16x16x32_bf16(aq[kc], bk, accS[ni], 0, 0, 0);
        }
      }
      const bool diag = (t == s);
#pragma unroll
      for (int ni = 0; ni < 4; ni++) {
        int col = t * 64 + ni * 16 + l15;
#pragma unroll
        for (int j = 0; j < 4; j++) {
          int row = qs + lhi * 4 + j;
          float p = (!diag || col <= row) ? __expf(accS[ni][j] * SCALE_F) : 0.f;
          rs[j] += p;
          int pr = lhi * 4 + j;
          P[pr * 64 + ((ni * 16 + l15) ^ ((pr & 7) * 8))] = f2bf(p);
        }
      }
      asm volatile("s_waitcnt lgkmcnt(0)" ::: "memory");
      __builtin_amdgcn_sched_barrier(0);
      bf16x8 ap[2];
#pragma unroll
      for (int ks = 0; ks < 2; ks++)
        ap[ks] = *(const bf16x8*)&P[l15 * 64 + ((ks * 32 + lhi * 8) ^ ((l15 & 7) * 8))];
#pragma unroll
      for (int nj = 0; nj < 8; nj++) {
        int row = nj * 16 + l15;
#pragma unroll
        for (int ks = 0; ks < 2; ks++) {
          bf16x8 bv = *(const bf16x8*)&Vs[row * 64 + ((ks * 32 + lhi * 8) ^ ((row & 7) * 8))];
          accO[nj] = __builtin_amdgcn_mfma_f32_16x16x32_bf16(ap[ks], bv, accO[nj], 0, 0, 0);
        }
      }
      cur ^= 1;
    }
#pragma unroll
    for (int j = 0; j < 4; j++) {
      float v = rs[j];
      v += __shfl_xor(v, 1);
      v += __shfl_xor(v, 2);
      v += __shfl_xor(v, 4);
      v += __shfl_xor(v, 8);
      rs[j] = 1.f / v;
    }
#pragma unroll
    for (int nj = 0; nj < 8; nj++)
#pragma unroll
      for (int j = 0; j < 4; j++) {
        int row = qs + lhi * 4 + j;
        int col = nj * 16 + l15;
        long rb = ((long)h * S_LEN + row) * 256 + col;
        float mo = bf2f(rawq[rb]) / (bf2f(rawq[rb + 128]) + 1e-8f);
        float ao = accO[nj][j] * rs[j];
        comb[(long)row * HID_DIM + h * HD + col] = f2bf(g * mo + (1.f - g) * ao);
      }
  }
}

// ---------------- delta v4: uvret fused into LDS staging + norm colsum ----------------

__global__ __launch_bounds__(256) void k_delta_part(
    const u16* __restrict__ knb, const u16* __restrict__ rawk,
    const u16* __restrict__ qkvb,
    float* __restrict__ dpart, float* __restrict__ npart) {
  __shared__ float knc[64][128];
  __shared__ u16 Uc[64][128];
  const int h = blockIdx.x, c = blockIdx.y, t = threadIdx.x;
  const long rb = ((long)h * S_LEN + (long)c * 64) * HD;
  const long rkb = ((long)h * S_LEN + (long)c * 64) * 256;
  const u16* vb = qkvb + HID_DIM + NKV * HD + h * HD + (long)c * 64 * QKV_N;
  for (int i = t; i < 1024; i += 256) {
    int r = i >> 4, cb = (i & 15) * 8;
    ushort4 k0 = *(const ushort4*)&knb[rb + (long)r * HD + cb];
    ushort4 k1 = *(const ushort4*)&knb[rb + (long)r * HD + cb + 4];
    knc[r][cb + 0] = bf2f(k0.x); knc[r][cb + 1] = bf2f(k0.y);
    knc[r][cb + 2] = bf2f(k0.z); knc[r][cb + 3] = bf2f(k0.w);
    knc[r][cb + 4] = bf2f(k1.x); knc[r][cb + 5] = bf2f(k1.y);
    knc[r][cb + 6] = bf2f(k1.z); knc[r][cb + 7] = bf2f(k1.w);
    ushort4 n0 = *(const ushort4*)&rawk[rkb + (long)r * 256 + cb];
    ushort4 n1 = *(const ushort4*)&rawk[rkb + (long)r * 256 + cb + 4];
    ushort4 dn0 = *(const ushort4*)&rawk[rkb + (long)r * 256 + 128 + cb];
    ushort4 dn1 = *(const ushort4*)&rawk[rkb + (long)r * 256 + 128 + cb + 4];
    ushort4 v0 = *(const ushort4*)&vb[(long)r * QKV_N + cb];
    ushort4 v1 = *(const ushort4*)&vb[(long)r * QKV_N + cb + 4];
    ushort4 u0, u1;
    u0.x = f2bf(bf2f(v0.x) - bf2f(n0.x) / (bf2f(dn0.x) + 1e-8f));
    u0.y = f2bf(bf2f(v0.y) - bf2f(n0.y) / (bf2f(dn0.y) + 1e-8f));
    u0.z = f2bf(bf2f(v0.z) - bf2f(n0.z) / (bf2f(dn0.z) + 1e-8f));
    u0.w = f2bf(bf2f(v0.w) - bf2f(n0.w) / (bf2f(dn0.w) + 1e-8f));
    u1.x = f2bf(bf2f(v1.x) - bf2f(n1.x) / (bf2f(dn1.x) + 1e-8f));
    u1.y = f2bf(bf2f(v1.y) - bf2f(n1.y) / (bf2f(dn1.y) + 1e-8f));
    u1.z = f2bf(bf2f(v1.z) - bf2f(n1.z) / (bf2f(dn1.z) + 1e-8f));
    u1.w = f2bf(bf2f(v1.w) - bf2f(n1.w) / (bf2f(dn1.w) + 1e-8f));
    *(ushort4*)&Uc[r][cb] = u0;
    *(ushort4*)&Uc[r][cb + 4] = u1;
  }
  __syncthreads();

  const int e = t & 127, dh = (t >> 7) * 64;
  float acc[64];
#pragma unroll
  for (int d = 0; d < 64; d++) acc[d] = 0.f;
  for (int s = 0; s < 64; s++) {
    float u = bf2f(Uc[s][e]);
#pragma unroll
    for (int dq = 0; dq < 16; dq++) {
      float4 k4 = *(const float4*)&knc[s][dh + dq * 4];
      acc[dq * 4 + 0] += k4.x * u;
      acc[dq * 4 + 1] += k4.y * u;
      acc[dq * 4 + 2] += k4.z * u;
      acc[dq * 4 + 3] += k4.w * u;
    }
  }
  long ob = (((long)c * NKV + h) * 128 + dh) * 128 + e;
#pragma unroll
  for (int d = 0; d < 64; d++) dpart[ob + (long)d * 128] = acc[d];

  {
    int j = e, half = t >> 7;
    float cs = 0.f;
#pragma unroll
    for (int s = 0; s < 32; s++) cs += knc[half * 32 + s][j];
    npart[(((long)c * 2 + half) * NKV + h) * 128 + j] = cs;
  }
}

// merged delta_reduce (bid<512) + norm_write (bid>=512)
__global__ void k_finish(const float* __restrict__ dpart, const float* __restrict__ npart,
                         const float* __restrict__ mem, const float* __restrict__ norm,
                         float* __restrict__ outmem, float* __restrict__ outn) {
  int bid = blockIdx.x;
  if (bid < 512) {
    long i = (long)bid * 256 + threadIdx.x;
    const long N = (long)NKV * HD * HD;
    float a = 0.f;
#pragma unroll 8
    for (int c = 0; c < 32; c++) a += dpart[(long)c * N + i];
    outmem[i] = mem[i] + a;
  } else {
    int b2 = bid - 512;
    int h = b2 >> 6, y = b2 & 63;
    int j = threadIdx.x & 127;
    int r = y * 2 + (threadIdx.x >> 7);
    float cs = 0.f;
#pragma unroll 8
    for (int cc = 0; cc < 64; cc++) cs += npart[((long)cc * NKV + h) * 128 + j];
    long o = (long)h * HD * HD + (long)r * HD + j;
    outn[o] = norm[o] + cs;
  }
}

// ---------------- host ----------------
// Phase order and arena identical to round 14 (peak ~154.5 MiB).

extern "C" void kernel_launch(void* const* d_in, const int* in_sizes, int n_in,
                              void* d_out, int out_size, void* d_ws, size_t ws_size,
                              hipStream_t stream) {
  const float* hs = (const float*)d_in[0];
  const int* pos = (const int*)d_in[1];
  const float* wq = (const float*)d_in[2];
  const float* wk = (const float*)d_in[3];
  const float* wv = (const float*)d_in[4];
  const float* wo = (const float*)d_in[5];
  const float* memf = (const float*)d_in[6];
  const float* normf = (const float*)d_in[7];
  const float* beta = (const float*)d_in[8];
  (void)in_sizes; (void)n_in; (void)out_size; (void)ws_size;

  float* out = (float*)d_out;
  float* out_mem = out + (long)S_LEN * HID_DIM;
  float* out_norm = out_mem + NKV * HD * HD;

  const size_t MB = 1u << 20;
  char* w = (char*)d_ws;
  u16* hsb    = (u16*)(w + 0);
  u16* qnb    = (u16*)(w + 0);
  u16* comb   = (u16*)(w + 0);
  u16* wT6    = (u16*)(w + 16 * MB);
  u16* rawq   = (u16*)(w + 16 * MB);
  u16* woT    = (u16*)(w + 16 * MB);
  u16* rawk   = (u16*)(w + 48 * MB);
  u16* bc     = (u16*)(w + 57 * MB);
  u16* vtb    = (u16*)(w + 57 * MB + 512 * 1024);
  u16* qkvb   = (u16*)(w + 66 * MB + 512 * 1024);
  u16* p0     = (u16*)(w + 90 * MB + 512 * 1024);
  u16* qrb    = (u16*)(w + 130 * MB + 512 * 1024);
  float* dpart= (float*)(w + 130 * MB + 512 * 1024);
  u16* p1     = (u16*)(w + 130 * MB + 512 * 1024);
  u16* krb    = (u16*)(w + 146 * MB + 512 * 1024);
  float* npart= (float*)(w + 146 * MB + 512 * 1024);
  u16* knb    = (u16*)(w + 150 * MB + 512 * 1024);

  // --- A: merged prep + QKV projection (bf16 out, A tri-buffer) ---
  k_prep<<<dim3(14336), dim3(256), 0, stream>>>(hs, hsb, wq, wk, wv, wT6);
  k_gemm8<192, 3><<<dim3(QKV_N / 192, S_LEN / 256, 1), dim3(512), 0, stream>>>(
      hsb, hsb, 1 << 30, wT6, qkvb, HID_DIM, HID_DIM, HID_DIM, QKV_N,
      0L, 0L, 0L, 1, 1);

  // --- D: qn + rope fused ---
  k_qnrope<<<dim3(S_LEN, NH + NKV), dim3(64), 0, stream>>>(
      qkvb, pos, qnb, qrb, knb, krb);

  // --- E: merged mid (V^T + mem^T + norm copy) ---
  k_mid<<<dim3(1056), dim3(256), 0, stream>>>(qkvb, vtb, memf, normf, bc);

  // --- F: retrieval raws, q+k merged into one dispatch (z = 40) ---
  k_gemm8<256, 2><<<dim3(1, 8, NH + NKV), dim3(512), 0, stream>>>(
      qnb, knb, NH, bc, rawq, HD, HD, HD, 256,
      (long)(S_LEN * HD), (long)(256 * HD), (long)(S_LEN * 256), NKV, 1);

  // --- H: attention with fused combine (reads rawq) ---
  k_flash4<<<dim3(16, NH), dim3(256), 0, stream>>>(qrb, krb, vtb, rawq, beta, comb);

  // --- K: memory / norm updates (reads qkvb v-cols + rawk) ---
  k_delta_part<<<dim3(NKV, 32), dim3(256), 0, stream>>>(knb, rawk, qkvb, dpart, npart);
  k_finish<<<dim3(1024), dim3(256), 0, stream>>>(dpart, npart, memf, normf, out_mem, out_norm);

  // --- J: wo^T; output projection (split-K2, bf16 partials + add) ---
  k_tr64<<<dim3(64, 64, 1), dim3(256), 0, stream>>>(
      wo, woT, HID_DIM, HID_DIM, 0L, 0L);
  k_gemm8<256, 2><<<dim3(HID_DIM / 256, S_LEN / 256, 2), dim3(512), 0, stream>>>(
      comb, comb, 1 << 30, woT, p0, 2048, HID_DIM, HID_DIM, HID_DIM,
      2048L, 2048L, (long)(p1 - p0), 2, 1);
  k_addp<<<dim3(S_LEN * HID_DIM / 2048), dim3(256), 0, stream>>>(p0, p1, out);
}

// Round 16
// 350.381 us; speedup vs baseline: 1.0201x; 1.0201x over previous
//
#include <hip/hip_runtime.h>

#define S_LEN 2048
#define HID_DIM 4096
#define NH 32
#define NKV 8
#define HD 128
#define QKV_N 6144
#define SCALE_F 0.08838834764831845f

typedef unsigned short u16;
typedef __attribute__((ext_vector_type(8))) __bf16 bf16x8;
typedef __attribute__((ext_vector_type(4))) float f32x4;

__device__ __forceinline__ u16 f2bf(float f) {
  unsigned u = __float_as_uint(f);
  return (u16)((u + 0x7fffu + ((u >> 16) & 1u)) >> 16);
}
__device__ __forceinline__ float bf2f(u16 v) {
  return __uint_as_float((unsigned)v << 16);
}

__device__ __forceinline__ void gl_lds16(const u16* g, u16* l) {
  __builtin_amdgcn_global_load_lds(
      (const __attribute__((address_space(1))) unsigned int*)g,
      (__attribute__((address_space(3))) unsigned int*)l, 16, 0, 0);
}

// ---------------- layout / prep kernels ----------------

__device__ __forceinline__ void tr64_body(const float* __restrict__ A, u16* __restrict__ O,
                                          int ld_in, int ld_out, int r0, int c0, int tid) {
  __shared__ float tile[64][65];
  int tx = tid & 31, ty = tid >> 5;
#pragma unroll
  for (int i = 0; i < 8; i++) {
    int r = ty + 8 * i;
    float2 v = *(const float2*)&A[(long)(r0 + r) * ld_in + c0 + 2 * tx];
    tile[r][2 * tx] = v.x;
    tile[r][2 * tx + 1] = v.y;
  }
  __syncthreads();
#pragma unroll
  for (int i = 0; i < 8; i++) {
    int c = ty + 8 * i;
    ushort2 o;
    o.x = f2bf(tile[2 * tx][c]);
    o.y = f2bf(tile[2 * tx + 1][c]);
    *(ushort2*)&O[(long)(c0 + c) * ld_out + r0 + 2 * tx] = o;
  }
}

__device__ __forceinline__ void tr64u_body(const u16* __restrict__ A, u16* __restrict__ O,
                                           int ld_in, int ld_out, int r0, int c0, int tid) {
  __shared__ u16 tileu[64][66];
  int tx = tid & 31, ty = tid >> 5;
#pragma unroll
  for (int i = 0; i < 8; i++) {
    int r = ty + 8 * i;
    ushort2 v = *(const ushort2*)&A[(long)(r0 + r) * ld_in + c0 + 2 * tx];
    tileu[r][2 * tx] = v.x;
    tileu[r][2 * tx + 1] = v.y;
  }
  __syncthreads();
#pragma unroll
  for (int i = 0; i < 8; i++) {
    int c = ty + 8 * i;
    ushort2 o;
    o.x = tileu[2 * tx][c];
    o.y = tileu[2 * tx + 1][c];
    *(ushort2*)&O[(long)(c0 + c) * ld_out + r0 + 2 * tx] = o;
  }
}

// merged: wq/wk/wv transposes (bid<6144) + wo transpose (6144..10239, -> d_out scratch)
// + hs f32->bf16 (bid>=10240)
__global__ void k_prep(const float* __restrict__ hs, u16* __restrict__ hsb,
                       const float* __restrict__ wq, const float* __restrict__ wk,
                       const float* __restrict__ wv, u16* __restrict__ wT6,
                       const float* __restrict__ wo, u16* __restrict__ woT) {
  int bid = blockIdx.x;
  if (bid < 6144) {
    const float* src; int ld, bx, by; long ooff;
    if (bid < 4096) { src = wq; ld = 4096; ooff = 0; bx = bid & 63; by = bid >> 6; }
    else if (bid < 5120) { int b = bid - 4096; src = wk; ld = 1024; ooff = (long)4096 * HID_DIM; bx = b & 15; by = b >> 4; }
    else { int b = bid - 5120; src = wv; ld = 1024; ooff = (long)5120 * HID_DIM; bx = b & 15; by = b >> 4; }
    tr64_body(src, wT6 + ooff, ld, HID_DIM, by * 64, bx * 64, threadIdx.x);
  } else if (bid < 10240) {
    int b = bid - 6144;
    tr64_body(wo, woT, HID_DIM, HID_DIM, (b >> 6) * 64, (b & 63) * 64, threadIdx.x);
  } else {
    long i = (long)(bid - 10240) * 256 + threadIdx.x;
    float4 v = ((const float4*)hs)[i];
    ushort4 o;
    o.x = f2bf(v.x); o.y = f2bf(v.y); o.z = f2bf(v.z); o.w = f2bf(v.w);
    ((ushort4*)hsb)[i] = o;
  }
}

// merged: V^T per kv head (bid<512) + mem^T (512..543) + norm copy (544..1055)
__global__ void k_mid(const u16* __restrict__ qkvb, u16* __restrict__ vtb,
                      const float* __restrict__ memf, const float* __restrict__ norm,
                      u16* __restrict__ bc) {
  int bid = blockIdx.x;
  if (bid < 512) {
    int z = bid >> 6, sub = bid & 63;
    int bx = sub & 1, by = sub >> 1;
    tr64u_body(qkvb + HID_DIM + NKV * HD + z * HD, vtb + (long)z * HD * S_LEN,
               QKV_N, S_LEN, by * 64, bx * 64, threadIdx.x);
  } else if (bid < 544) {
    int b = bid - 512;
    int h = b >> 2, sub = b & 3;
    tr64_body(memf + (long)h * HD * HD, bc + (long)h * 32768,
              HD, HD, (sub >> 1) * 64, (sub & 1) * 64, threadIdx.x);
  } else {
    int cid = bid - 544;
    int h = cid >> 6, chunk = cid & 63;
    int i = chunk * 256 + threadIdx.x;
    bc[(long)h * 32768 + 16384 + i] = f2bf(norm[(long)h * 16384 + i]);
  }
}

// ---------------- GEMM v9: 8-phase 256xBN, BK=64, A depth ATRI ----------------
// ATRI=2 is the round-7-proven schedule (QKV/retrieval/out-proj all use it).

template <int BN, int ATRI>
__global__ __launch_bounds__(512, 2) void k_gemm8(
    const u16* __restrict__ A, const u16* __restrict__ A2, int zsplit,
    const u16* __restrict__ Bt, void* __restrict__ Cv,
    int kloop, int lda, int ldb, int ldc,
    long strideA, long strideB, long strideC, int bmodB, int obf) {
  constexpr int NBG = BN / 64;
  constexpr int NNI = BN / 64;
  constexpr int AHEAD = ATRI - 1;
  constexpr int WAITN = NBG + 4 * (AHEAD - 1);
  constexpr int AELT = 16384;
  constexpr int ABYTES = ATRI * AELT;
  constexpr int BN64 = BN * 64;
  __shared__ __align__(16) u16 lds[ABYTES + 2 * BN64];
  const int bz = blockIdx.z;
  const u16* Ap = (bz < zsplit) ? (A + (long)bz * strideA)
                                : (A2 + (long)(bz - zsplit) * strideA);
  const u16* Bp = Bt + (long)(bz % bmodB) * strideB;
  const long coff = (long)bz * strideC;

  const int gx = gridDim.x, gy = gridDim.y;
  const int nwg = gx * gy;
  int id = blockIdx.y * gx + blockIdx.x;
  if (!(nwg & 7)) { int q = nwg >> 3; id = (id & 7) * q + (id >> 3); }
  const int m0 = (id % gy) * 256;
  const int n0 = (id / gy) * BN;

  const int tid = threadIdx.x, wid = tid >> 6, lane = tid & 63;
  const int l15 = lane & 15, lhi = lane >> 4;
  const int wm = wid >> 2, wn = wid & 3;

  const int srow = (wid << 3) + (lane >> 3);
  const int ssw = ((lane & 7) ^ (lane >> 3)) * 8;
  auto stA = [&](int ab, int g, long kt) {
    gl_lds16(Ap + (long)(m0 + g * 64 + srow) * lda + kt + ssw,
             &lds[ab * AELT + (g * 64 + (wid << 3)) * 64]);
  };
  auto stB = [&](int d, int g, long kt) {
    gl_lds16(Bp + (long)(n0 + g * 64 + srow) * ldb + kt + ssw,
             &lds[ABYTES + d * BN64 + (g * 64 + (wid << 3)) * 64]);
  };

  const int swb = l15 & 7;
  const int aBase = (wm * 128 + l15) * 64;
  const int bBase = (wn * (BN / 4) + l15) * 64;
  const int ko0 = (lhi ^ swb) * 8;
  const int ko1 = ((4 + lhi) ^ swb) * 8;

  const int KT = kloop >> 6;
  const int NIT = KT >> 1;

  f32x4 acc[8][NNI];
#pragma unroll
  for (int i = 0; i < 8; i++)
#pragma unroll
    for (int j = 0; j < NNI; j++) acc[i][j] = (f32x4){0.f, 0.f, 0.f, 0.f};

#pragma unroll
  for (int g = 0; g < 4; g++) stA(0, g, 0);
#pragma unroll
  for (int g = 0; g < NBG; g++) stB(0, g, 0);
  if (ATRI > 2) {
#pragma unroll
    for (int g = 0; g < 4; g++) stA(1, g, 64);
  }
#pragma unroll
  for (int g = 0; g < NBG; g++) stB(1, g, 64);
  asm volatile("s_waitcnt vmcnt(%0)" :: "i"(WAITN) : "memory");
  __builtin_amdgcn_s_barrier();
  asm volatile("" ::: "memory");

  int ab0 = 0;
  for (int t = 0; t < NIT; ++t) {
    const int uS0 = 2 * t + AHEAD;
    const int uS1 = 2 * t + 1 + AHEAD;
    const int abR0 = ab0;
    const int abR1 = (ab0 + 1 < ATRI) ? (ab0 + 1) : 0;
    const int abS0 = (ab0 + AHEAD < ATRI) ? (ab0 + AHEAD) : (ab0 + AHEAD - ATRI);
    const int abS1 = (abS0 + 1 < ATRI) ? (abS0 + 1) : 0;
    const long kA0 = (long)uS0 * 64, kA1 = (long)uS1 * 64;
    const long kB0 = (long)(2 * t + 2) * 64;
    const long kB1 = (long)(2 * t + 3) * 64;
    const bool sA0 = uS0 < KT, sA1 = uS1 < KT;
    const bool sB0 = (2 * t + 2) < KT, sB1 = (2 * t + 3) < KT;
    const bool last = (t + 1 == NIT);

    {
      const u16* la = &lds[abR0 * AELT];
      const u16* lbB = &lds[ABYTES];
      bf16x8 Bf[NNI][2];
#pragma unroll
      for (int p = 0; p < 4; p++) {
        if (p == 0) {
#pragma unroll
          for (int ni = 0; ni < NNI; ni++) {
            Bf[ni][0] = *(const bf16x8*)&lbB[bBase + ni * 1024 + ko0];
            Bf[ni][1] = *(const bf16x8*)&lbB[bBase + ni * 1024 + ko1];
          }
        }
        bf16x8 a0k0 = *(const bf16x8*)&la[aBase + (2 * p) * 1024 + ko0];
        bf16x8 a0k1 = *(const bf16x8*)&la[aBase + (2 * p) * 1024 + ko1];
        bf16x8 a1k0 = *(const bf16x8*)&la[aBase + (2 * p + 1) * 1024 + ko0];
        bf16x8 a1k1 = *(const bf16x8*)&la[aBase + (2 * p + 1) * 1024 + ko1];
        if (p == 0) { if (sA0) { stA(abS0, 0, kA0); stA(abS0, 1, kA0); } }
        else if (p == 1) { if (sA0) { stA(abS0, 2, kA0); stA(abS0, 3, kA0); } }
        else if (p == 2) { if (sB0) { stB(0, 0, kB0); stB(0, 1, kB0); } }
        else {
          if (sB0) { stB(0, 2, kB0); if (NBG > 3) stB(0, 3, kB0); }
        }
        asm volatile("" ::: "memory");
        if (p == 3) {
          if (last) asm volatile("s_waitcnt vmcnt(0)" ::: "memory");
          else      asm volatile("s_waitcnt vmcnt(%0)" :: "i"(WAITN) : "memory");
        }
        __builtin_amdgcn_s_barrier();
        asm volatile("" ::: "memory");
        __builtin_amdgcn_s_setprio(1);
#pragma unroll
        for (int ni = 0; ni < NNI; ni++) {
          acc[2 * p][ni] = __builtin_amdgcn_mfma_f32_16x16x32_bf16(a0k0, Bf[ni][0], acc[2 * p][ni], 0, 0, 0);
          acc[2 * p][ni] = __builtin_amdgcn_mfma_f32_16x16x32_bf16(a0k1, Bf[ni][1], acc[2 * p][ni], 0, 0, 0);
          acc[2 * p + 1][ni] = __builtin_amdgcn_mfma_f32_16x16x32_bf16(a1k0, Bf[ni][0], acc[2 * p + 1][ni], 0, 0, 0);
          acc[2 * p + 1][ni] = __builtin_amdgcn_mfma_f32_16x16x32_bf16(a1k1, Bf[ni][1], acc[2 * p + 1][ni], 0, 0, 0);
        }
        __builtin_amdgcn_s_setprio(0);
        asm volatile("" ::: "memory");
        __builtin_amdgcn_s_barrier();
        asm volatile("" ::: "memory");
      }
    }
    {
      const u16* la = &lds[abR1 * AELT];
      const u16* lbB = &lds[ABYTES + BN64];
      bf16x8 Bf[NNI][2];
#pragma unroll
      for (int p = 0; p < 4; p++) {
        if (p == 0) {
#pragma unroll
          for (int ni = 0; ni < NNI; ni++) {
            Bf[ni][0] = *(const bf16x8*)&lbB[bBase + ni * 1024 + ko0];
            Bf[ni][1] = *(const bf16x8*)&lbB[bBase + ni * 1024 + ko1];
          }
        }
        bf16x8 a0k0 = *(const bf16x8*)&la[aBase + (2 * p) * 1024 + ko0];
        bf16x8 a0k1 = *(const bf16x8*)&la[aBase + (2 * p) * 1024 + ko1];
        bf16x8 a1k0 = *(const bf16x8*)&la[aBase + (2 * p + 1) * 1024 + ko0];
        bf16x8 a1k1 = *(const bf16x8*)&la[aBase + (2 * p + 1) * 1024 + ko1];
        if (p == 0) { if (sA1) { stA(abS1, 0, kA1); stA(abS1, 1, kA1); } }
        else if (p == 1) { if (sA1) { stA(abS1, 2, kA1); stA(abS1, 3, kA1); } }
        else if (p == 2) { if (sB1) { stB(1, 0, kB1); stB(1, 1, kB1); } }
        else {
          if (sB1) { stB(1, 2, kB1); if (NBG > 3) stB(1, 3, kB1); }
        }
        asm volatile("" ::: "memory");
        if (p == 3 && !last)
          asm volatile("s_waitcnt vmcnt(%0)" :: "i"(WAITN) : "memory");
        __builtin_amdgcn_s_barrier();
        asm volatile("" ::: "memory");
        __builtin_amdgcn_s_setprio(1);
#pragma unroll
        for (int ni = 0; ni < NNI; ni++) {
          acc[2 * p][ni] = __builtin_amdgcn_mfma_f32_16x16x32_bf16(a0k0, Bf[ni][0], acc[2 * p][ni], 0, 0, 0);
          acc[2 * p][ni] = __builtin_amdgcn_mfma_f32_16x16x32_bf16(a0k1, Bf[ni][1], acc[2 * p][ni], 0, 0, 0);
          acc[2 * p + 1][ni] = __builtin_amdgcn_mfma_f32_16x16x32_bf16(a1k0, Bf[ni][0], acc[2 * p + 1][ni], 0, 0, 0);
          acc[2 * p + 1][ni] = __builtin_amdgcn_mfma_f32_16x16x32_bf16(a1k1, Bf[ni][1], acc[2 * p + 1][ni], 0, 0, 0);
        }
        __builtin_amdgcn_s_setprio(0);
        asm volatile("" ::: "memory");
        __builtin_amdgcn_s_barrier();
        asm volatile("" ::: "memory");
      }
    }
    ab0 = (ab0 + 2 < ATRI) ? (ab0 + 2) : (ab0 + 2 - ATRI);
  }

#pragma unroll
  for (int mi = 0; mi < 8; mi++)
#pragma unroll
    for (int ni = 0; ni < NNI; ni++)
#pragma unroll
      for (int j = 0; j < 4; j++) {
        long row = m0 + wm * 128 + mi * 16 + lhi * 4 + j;
        long col = n0 + wn * (BN / 4) + ni * 16 + l15;
        if (obf)
          ((u16*)Cv)[coff + row * ldc + col] = f2bf(acc[mi][ni][j]);
        else
          ((float*)Cv)[coff + row * ldc + col] = acc[mi][ni][j];
      }
}

// ---------------- split-K add epilogue ----------------

__global__ void k_addp(const u16* __restrict__ p0, const u16* __restrict__ p1,
                       float* __restrict__ out) {
  long i = ((long)blockIdx.x * 256 + threadIdx.x) * 8;
  ushort4 a0 = *(const ushort4*)&p0[i], a1 = *(const ushort4*)&p0[i + 4];
  ushort4 b0 = *(const ushort4*)&p1[i], b1 = *(const ushort4*)&p1[i + 4];
  float4 o0, o1;
  o0.x = bf2f(a0.x) + bf2f(b0.x); o0.y = bf2f(a0.y) + bf2f(b0.y);
  o0.z = bf2f(a0.z) + bf2f(b0.z); o0.w = bf2f(a0.w) + bf2f(b0.w);
  o1.x = bf2f(a1.x) + bf2f(b1.x); o1.y = bf2f(a1.y) + bf2f(b1.y);
  o1.z = bf2f(a1.z) + bf2f(b1.z); o1.w = bf2f(a1.w) + bf2f(b1.w);
  *(float4*)&out[i] = o0;
  *(float4*)&out[i + 4] = o1;
}

// ---------------- fused qn + rope (bf16 qkv input) ----------------

__global__ void k_qnrope(const u16* __restrict__ qkv, const int* __restrict__ pos,
                         u16* __restrict__ qnb, u16* __restrict__ qrb,
                         u16* __restrict__ knb, u16* __restrict__ krb) {
  int s = blockIdx.x, y = blockIdx.y, l = threadIdx.x;  // 64 threads
  bool isq = y < NH;
  int h = isq ? y : y - NH;
  const u16* row = qkv + (long)s * QKV_N + (isq ? h * HD : HID_DIM + h * HD);
  float x0 = bf2f(row[l]), x1 = bf2f(row[l + 64]);
  float f0 = x0 > 0.f ? x0 + 1.f : __expf(x0);
  float f1 = x1 > 0.f ? x1 + 1.f : __expf(x1);
  float sum = f0 + f1;
#pragma unroll
  for (int m = 32; m >= 1; m >>= 1) sum += __shfl_xor(sum, m);
  float inv = 1.f / (sum + 1e-8f);
  float y0 = f0 * inv, y1 = f1 * inv;
  long o = ((long)h * S_LEN + s) * HD;
  float p = (float)pos[s];
  float ang = p * expf(-(float)l * (9.210340371976184f / 64.0f));
  float c = cosf(ang), sn = sinf(ang);
  u16 r0 = f2bf(x0 * c - x1 * sn), r1 = f2bf(x1 * c + x0 * sn);
  if (isq) {
    qnb[o + l] = f2bf(y0); qnb[o + l + 64] = f2bf(y1);
    qrb[o + l] = r0; qrb[o + l + 64] = r1;
  } else {
    knb[o + l] = f2bf(y0); knb[o + l + 64] = f2bf(y1);
    krb[o + l] = r0; krb[o + l + 64] = r1;
  }
}

// ---------------- flash attention v4: fused combine epilogue ----------------

__global__ __launch_bounds__(256, 2) void k_flash4(
    const u16* __restrict__ qr, const u16* __restrict__ kr,
    const u16* __restrict__ vt, const u16* __restrict__ rawq,
    const float* __restrict__ beta, u16* __restrict__ comb) {
  __shared__ u16 KV[2][16384];
  __shared__ u16 Ps[4][16 * 64];
  const int bx = blockIdx.x, h = blockIdx.y;
  const int hk = h >> 2;
  const int tid = threadIdx.x, wid = tid >> 6, lane = tid & 63;
  const int l15 = lane & 15, lhi = lane >> 4;
  const u16* qbase = qr + (long)h * S_LEN * HD;
  const u16* kb0 = kr + (long)hk * S_LEN * HD;
  const u16* vb0 = vt + (long)hk * HD * S_LEN;
  u16* P = Ps[wid];
  const float g = 1.f / (1.f + __expf(-beta[0]));

  int kr_r[4], kr_sc[4], vr_r[4], vr_sc[4];
#pragma unroll
  for (int it = 0; it < 4; it++) {
    int chunk = it * 4 + wid;
    kr_r[it] = chunk * 4 + (lane >> 4);
    kr_sc[it] = ((lane & 15) * 8) ^ ((kr_r[it] & 7) * 8);
    vr_r[it] = chunk * 8 + (lane >> 3);
    vr_sc[it] = ((lane & 7) * 8) ^ ((vr_r[it] & 7) * 8);
  }

  for (int si = 0; si < 2; si++) {
    const int s = si ? (31 - bx) : bx;
    const int qs = s * 64 + wid * 16;
    bf16x8 aq[4];
#pragma unroll
    for (int kc = 0; kc < 4; kc++)
      aq[kc] = *(const bf16x8*)&qbase[(long)(qs + l15) * HD + kc * 32 + lhi * 8];
    f32x4 accO[8];
#pragma unroll
    for (int i = 0; i < 8; i++) accO[i] = (f32x4){0.f, 0.f, 0.f, 0.f};
    float rs[4] = {0.f, 0.f, 0.f, 0.f};

    if (si) __syncthreads();
    {
      u16* Kb = KV[0];
#pragma unroll
      for (int it = 0; it < 4; it++)
        gl_lds16(kb0 + (long)kr_r[it] * HD + kr_sc[it], &Kb[(it * 4 + wid) * 512]);
#pragma unroll
      for (int it = 0; it < 4; it++)
        gl_lds16(vb0 + (long)vr_r[it] * S_LEN + vr_sc[it], &Kb[8192 + (it * 4 + wid) * 512]);
    }
    int cur = 0;

    for (int t = 0; t <= s; t++) {
      asm volatile("s_waitcnt vmcnt(0)" ::: "memory");
      __syncthreads();
      if (t < s) {
        u16* Kb = KV[cur ^ 1];
        const long kt = (long)(t + 1) * 64;
#pragma unroll
        for (int it = 0; it < 4; it++)
          gl_lds16(kb0 + (kt + kr_r[it]) * HD + kr_sc[it], &Kb[(it * 4 + wid) * 512]);
#pragma unroll
        for (int it = 0; it < 4; it++)
          gl_lds16(vb0 + (long)vr_r[it] * S_LEN + kt + vr_sc[it], &Kb[8192 + (it * 4 + wid) * 512]);
      }
      const u16* Ks = KV[cur];
      const u16* Vs = Ks + 8192;

      f32x4 accS[4];
#pragma unroll
      for (int i = 0; i < 4; i++) accS[i] = (f32x4){0.f, 0.f, 0.f, 0.f};
#pragma unroll
      for (int ni = 0; ni < 4; ni++) {
        int row = ni * 16 + l15;
#pragma unroll
        for (int kc = 0; kc < 4; kc++) {
          bf16x8 bk = *(const bf16x8*)&Ks[row * 128 + ((kc * 32 + lhi * 8) ^ ((row & 7) * 8))];
          accS[ni] = __builtin_amdgcn_mfma_f32_16x16x32_bf16(aq[kc], bk, accS[ni], 0, 0, 0);
        }
      }
      const bool diag = (t == s);
#pragma unroll
      for (int ni = 0; ni < 4; ni++) {
        int col = t * 64 + ni * 16 + l15;
#pragma unroll
        for (int j = 0; j < 4; j++) {
          int row = qs + lhi * 4 + j;
          float p = (!diag || col <= row) ? __expf(accS[ni][j] * SCALE_F) : 0.f;
          rs[j] += p;
          int pr = lhi * 4 + j;
          P[pr * 64 + ((ni * 16 + l15) ^ ((pr & 7) * 8))] = f2bf(p);
        }
      }
      asm volatile("s_waitcnt lgkmcnt(0)" ::: "memory");
      __builtin_amdgcn_sched_barrier(0);
      bf16x8 ap[2];
#pragma unroll
      for (int ks = 0; ks < 2; ks++)
        ap[ks] = *(const bf16x8*)&P[l15 * 64 + ((ks * 32 + lhi * 8) ^ ((l15 & 7) * 8))];
#pragma unroll
      for (int nj = 0; nj < 8; nj++) {
        int row = nj * 16 + l15;
#pragma unroll
        for (int ks = 0; ks < 2; ks++) {
          bf16x8 bv = *(const bf16x8*)&Vs[row * 64 + ((ks * 32 + lhi * 8) ^ ((row & 7) * 8))];
          accO[nj] = __builtin_amdgcn_mfma_f32_16x16x32_bf16(ap[ks], bv, accO[nj], 0, 0, 0);
        }
      }
      cur ^= 1;
    }
#pragma unroll
    for (int j = 0; j < 4; j++) {
      float v = rs[j];
      v += __shfl_xor(v, 1);
      v += __shfl_xor(v, 2);
      v += __shfl_xor(v, 4);
      v += __shfl_xor(v, 8);
      rs[j] = 1.f / v;
    }
#pragma unroll
    for (int nj = 0; nj < 8; nj++)
#pragma unroll
      for (int j = 0; j < 4; j++) {
        int row = qs + lhi * 4 + j;
        int col = nj * 16 + l15;
        long rb = ((long)h * S_LEN + row) * 256 + col;
        float mo = bf2f(rawq[rb]) / (bf2f(rawq[rb + 128]) + 1e-8f);
        float ao = accO[nj][j] * rs[j];
        comb[(long)row * HID_DIM + h * HD + col] = f2bf(g * mo + (1.f - g) * ao);
      }
  }
}

// ---------------- delta v4: uvret fused into LDS staging + norm colsum ----------------

__global__ __launch_bounds__(256) void k_delta_part(
    const u16* __restrict__ knb, const u16* __restrict__ rawk,
    const u16* __restrict__ qkvb,
    float* __restrict__ dpart, float* __restrict__ npart) {
  __shared__ float knc[64][128];
  __shared__ u16 Uc[64][128];
  const int h = blockIdx.x, c = blockIdx.y, t = threadIdx.x;
  const long rb = ((long)h * S_LEN + (long)c * 64) * HD;
  const long rkb = ((long)h * S_LEN + (long)c * 64) * 256;
  const u16* vb = qkvb + HID_DIM + NKV * HD + h * HD + (long)c * 64 * QKV_N;
  for (int i = t; i < 1024; i += 256) {
    int r = i >> 4, cb = (i & 15) * 8;
    ushort4 k0 = *(const ushort4*)&knb[rb + (long)r * HD + cb];
    ushort4 k1 = *(const ushort4*)&knb[rb + (long)r * HD + cb + 4];
    knc[r][cb + 0] = bf2f(k0.x); knc[r][cb + 1] = bf2f(k0.y);
    knc[r][cb + 2] = bf2f(k0.z); knc[r][cb + 3] = bf2f(k0.w);
    knc[r][cb + 4] = bf2f(k1.x); knc[r][cb + 5] = bf2f(k1.y);
    knc[r][cb + 6] = bf2f(k1.z); knc[r][cb + 7] = bf2f(k1.w);
    ushort4 n0 = *(const ushort4*)&rawk[rkb + (long)r * 256 + cb];
    ushort4 n1 = *(const ushort4*)&rawk[rkb + (long)r * 256 + cb + 4];
    ushort4 dn0 = *(const ushort4*)&rawk[rkb + (long)r * 256 + 128 + cb];
    ushort4 dn1 = *(const ushort4*)&rawk[rkb + (long)r * 256 + 128 + cb + 4];
    ushort4 v0 = *(const ushort4*)&vb[(long)r * QKV_N + cb];
    ushort4 v1 = *(const ushort4*)&vb[(long)r * QKV_N + cb + 4];
    ushort4 u0, u1;
    u0.x = f2bf(bf2f(v0.x) - bf2f(n0.x) / (bf2f(dn0.x) + 1e-8f));
    u0.y = f2bf(bf2f(v0.y) - bf2f(n0.y) / (bf2f(dn0.y) + 1e-8f));
    u0.z = f2bf(bf2f(v0.z) - bf2f(n0.z) / (bf2f(dn0.z) + 1e-8f));
    u0.w = f2bf(bf2f(v0.w) - bf2f(n0.w) / (bf2f(dn0.w) + 1e-8f));
    u1.x = f2bf(bf2f(v1.x) - bf2f(n1.x) / (bf2f(dn1.x) + 1e-8f));
    u1.y = f2bf(bf2f(v1.y) - bf2f(n1.y) / (bf2f(dn1.y) + 1e-8f));
    u1.z = f2bf(bf2f(v1.z) - bf2f(n1.z) / (bf2f(dn1.z) + 1e-8f));
    u1.w = f2bf(bf2f(v1.w) - bf2f(n1.w) / (bf2f(dn1.w) + 1e-8f));
    *(ushort4*)&Uc[r][cb] = u0;
    *(ushort4*)&Uc[r][cb + 4] = u1;
  }
  __syncthreads();

  const int e = t & 127, dh = (t >> 7) * 64;
  float acc[64];
#pragma unroll
  for (int d = 0; d < 64; d++) acc[d] = 0.f;
  for (int s = 0; s < 64; s++) {
    float u = bf2f(Uc[s][e]);
#pragma unroll
    for (int dq = 0; dq < 16; dq++) {
      float4 k4 = *(const float4*)&knc[s][dh + dq * 4];
      acc[dq * 4 + 0] += k4.x * u;
      acc[dq * 4 + 1] += k4.y * u;
      acc[dq * 4 + 2] += k4.z * u;
      acc[dq * 4 + 3] += k4.w * u;
    }
  }
  long ob = (((long)c * NKV + h) * 128 + dh) * 128 + e;
#pragma unroll
  for (int d = 0; d < 64; d++) dpart[ob + (long)d * 128] = acc[d];

  {
    int j = e, half = t >> 7;
    float cs = 0.f;
#pragma unroll
    for (int s = 0; s < 32; s++) cs += knc[half * 32 + s][j];
    npart[(((long)c * 2 + half) * NKV + h) * 128 + j] = cs;
  }
}

// merged delta_reduce (bid<512) + norm_write (bid>=512)
__global__ void k_finish(const float* __restrict__ dpart, const float* __restrict__ npart,
                         const float* __restrict__ mem, const float* __restrict__ norm,
                         float* __restrict__ outmem, float* __restrict__ outn) {
  int bid = blockIdx.x;
  if (bid < 512) {
    long i = (long)bid * 256 + threadIdx.x;
    const long N = (long)NKV * HD * HD;
    float a = 0.f;
#pragma unroll 8
    for (int c = 0; c < 32; c++) a += dpart[(long)c * N + i];
    outmem[i] = mem[i] + a;
  } else {
    int b2 = bid - 512;
    int h = b2 >> 6, y = b2 & 63;
    int j = threadIdx.x & 127;
    int r = y * 2 + (threadIdx.x >> 7);
    float cs = 0.f;
#pragma unroll 8
    for (int cc = 0; cc < 64; cc++) cs += npart[((long)cc * NKV + h) * 128 + j];
    long o = (long)h * HD * HD + (long)r * HD + j;
    outn[o] = norm[o] + cs;
  }
}

// ---------------- host ----------------
// Phase order: A (prep incl wo^T->d_out scratch + QKV), D (qnrope), E (mid),
// F (retrieval), H (flash+combine), K (delta/finish), J (out-proj + addp).
// woT lives in d_out[0,32MB) — dead until addp overwrites it with final out.

extern "C" void kernel_launch(void* const* d_in, const int* in_sizes, int n_in,
                              void* d_out, int out_size, void* d_ws, size_t ws_size,
                              hipStream_t stream) {
  const float* hs = (const float*)d_in[0];
  const int* pos = (const int*)d_in[1];
  const float* wq = (const float*)d_in[2];
  const float* wk = (const float*)d_in[3];
  const float* wv = (const float*)d_in[4];
  const float* wo = (const float*)d_in[5];
  const float* memf = (const float*)d_in[6];
  const float* normf = (const float*)d_in[7];
  const float* beta = (const float*)d_in[8];
  (void)in_sizes; (void)n_in; (void)out_size; (void)ws_size;

  float* out = (float*)d_out;
  float* out_mem = out + (long)S_LEN * HID_DIM;
  float* out_norm = out_mem + NKV * HD * HD;
  u16* woT = (u16*)d_out;  // scratch over out[0,32MB), consumed before addp

  const size_t MB = 1u << 20;
  char* w = (char*)d_ws;
  u16* hsb    = (u16*)(w + 0);
  u16* qnb    = (u16*)(w + 0);
  u16* comb   = (u16*)(w + 0);
  u16* wT6    = (u16*)(w + 16 * MB);
  u16* rawq   = (u16*)(w + 16 * MB);
  u16* rawk   = (u16*)(w + 48 * MB);
  u16* bc     = (u16*)(w + 57 * MB);
  u16* vtb    = (u16*)(w + 57 * MB + 512 * 1024);
  u16* qkvb   = (u16*)(w + 66 * MB + 512 * 1024);
  u16* p0     = (u16*)(w + 90 * MB + 512 * 1024);
  u16* qrb    = (u16*)(w + 130 * MB + 512 * 1024);
  float* dpart= (float*)(w + 130 * MB + 512 * 1024);
  u16* p1     = (u16*)(w + 130 * MB + 512 * 1024);
  u16* krb    = (u16*)(w + 146 * MB + 512 * 1024);
  float* npart= (float*)(w + 146 * MB + 512 * 1024);
  u16* knb    = (u16*)(w + 150 * MB + 512 * 1024);

  // --- A: merged prep (hs conv + all 4 weight transposes) + QKV projection ---
  k_prep<<<dim3(18432), dim3(256), 0, stream>>>(hs, hsb, wq, wk, wv, wT6, wo, woT);
  k_gemm8<192, 2><<<dim3(QKV_N / 192, S_LEN / 256, 1), dim3(512), 0, stream>>>(
      hsb, hsb, 1 << 30, wT6, qkvb, HID_DIM, HID_DIM, HID_DIM, QKV_N,
      0L, 0L, 0L, 1, 1);

  // --- D: qn + rope fused ---
  k_qnrope<<<dim3(S_LEN, NH + NKV), dim3(64), 0, stream>>>(
      qkvb, pos, qnb, qrb, knb, krb);

  // --- E: merged mid (V^T + mem^T + norm copy) ---
  k_mid<<<dim3(1056), dim3(256), 0, stream>>>(qkvb, vtb, memf, normf, bc);

  // --- F: retrieval raws, q+k merged into one dispatch (z = 40) ---
  k_gemm8<256, 2><<<dim3(1, 8, NH + NKV), dim3(512), 0, stream>>>(
      qnb, knb, NH, bc, rawq, HD, HD, HD, 256,
      (long)(S_LEN * HD), (long)(256 * HD), (long)(S_LEN * 256), NKV, 1);

  // --- H: attention with fused combine (reads rawq) ---
  k_flash4<<<dim3(16, NH), dim3(256), 0, stream>>>(qrb, krb, vtb, rawq, beta, comb);

  // --- K: memory / norm updates (reads qkvb v-cols + rawk) ---
  k_delta_part<<<dim3(NKV, 32), dim3(256), 0, stream>>>(knb, rawk, qkvb, dpart, npart);
  k_finish<<<dim3(1024), dim3(256), 0, stream>>>(dpart, npart, memf, normf, out_mem, out_norm);

  // --- J: output projection (split-K2, bf16 partials + add; reads woT from d_out) ---
  k_gemm8<256, 2><<<dim3(HID_DIM / 256, S_LEN / 256, 2), dim3(512), 0, stream>>>(
      comb, comb, 1 << 30, woT, p0, 2048, HID_DIM, HID_DIM, HID_DIM,
      2048L, 2048L, (long)(p1 - p0), 2, 1);
  k_addp<<<dim3(S_LEN * HID_DIM / 2048), dim3(256), 0, stream>>>(p0, p1, out);
}

// Round 17
// 349.779 us; speedup vs baseline: 1.0219x; 1.0017x over previous
//
#include <hip/hip_runtime.h>

#define S_LEN 2048
#define HID_DIM 4096
#define NH 32
#define NKV 8
#define HD 128
#define QKV_N 6144
#define SCALE_F 0.08838834764831845f

typedef unsigned short u16;
typedef __attribute__((ext_vector_type(8))) __bf16 bf16x8;
typedef __attribute__((ext_vector_type(4))) float f32x4;

__device__ __forceinline__ u16 f2bf(float f) {
  unsigned u = __float_as_uint(f);
  return (u16)((u + 0x7fffu + ((u >> 16) & 1u)) >> 16);
}
__device__ __forceinline__ float bf2f(u16 v) {
  return __uint_as_float((unsigned)v << 16);
}

__device__ __forceinline__ void gl_lds16(const u16* g, u16* l) {
  __builtin_amdgcn_global_load_lds(
      (const __attribute__((address_space(1))) unsigned int*)g,
      (__attribute__((address_space(3))) unsigned int*)l, 16, 0, 0);
}

// ---------------- layout / prep kernels ----------------

__device__ __forceinline__ void tr64_body(const float* __restrict__ A, u16* __restrict__ O,
                                          int ld_in, int ld_out, int r0, int c0, int tid) {
  __shared__ float tile[64][65];
  int tx = tid & 31, ty = tid >> 5;
#pragma unroll
  for (int i = 0; i < 8; i++) {
    int r = ty + 8 * i;
    float2 v = *(const float2*)&A[(long)(r0 + r) * ld_in + c0 + 2 * tx];
    tile[r][2 * tx] = v.x;
    tile[r][2 * tx + 1] = v.y;
  }
  __syncthreads();
#pragma unroll
  for (int i = 0; i < 8; i++) {
    int c = ty + 8 * i;
    ushort2 o;
    o.x = f2bf(tile[2 * tx][c]);
    o.y = f2bf(tile[2 * tx + 1][c]);
    *(ushort2*)&O[(long)(c0 + c) * ld_out + r0 + 2 * tx] = o;
  }
}

__device__ __forceinline__ void tr64u_body(const u16* __restrict__ A, u16* __restrict__ O,
                                           int ld_in, int ld_out, int r0, int c0, int tid) {
  __shared__ u16 tileu[64][66];
  int tx = tid & 31, ty = tid >> 5;
#pragma unroll
  for (int i = 0; i < 8; i++) {
    int r = ty + 8 * i;
    ushort2 v = *(const ushort2*)&A[(long)(r0 + r) * ld_in + c0 + 2 * tx];
    tileu[r][2 * tx] = v.x;
    tileu[r][2 * tx + 1] = v.y;
  }
  __syncthreads();
#pragma unroll
  for (int i = 0; i < 8; i++) {
    int c = ty + 8 * i;
    ushort2 o;
    o.x = tileu[2 * tx][c];
    o.y = tileu[2 * tx + 1][c];
    *(ushort2*)&O[(long)(c0 + c) * ld_out + r0 + 2 * tx] = o;
  }
}

// merged: wq/wk/wv transposes (bid<6144) + wo transpose (6144..10239, -> d_out scratch)
// + hs f32->bf16 (bid>=10240)
__global__ void k_prep(const float* __restrict__ hs, u16* __restrict__ hsb,
                       const float* __restrict__ wq, const float* __restrict__ wk,
                       const float* __restrict__ wv, u16* __restrict__ wT6,
                       const float* __restrict__ wo, u16* __restrict__ woT) {
  int bid = blockIdx.x;
  if (bid < 6144) {
    const float* src; int ld, bx, by; long ooff;
    if (bid < 4096) { src = wq; ld = 4096; ooff = 0; bx = bid & 63; by = bid >> 6; }
    else if (bid < 5120) { int b = bid - 4096; src = wk; ld = 1024; ooff = (long)4096 * HID_DIM; bx = b & 15; by = b >> 4; }
    else { int b = bid - 5120; src = wv; ld = 1024; ooff = (long)5120 * HID_DIM; bx = b & 15; by = b >> 4; }
    tr64_body(src, wT6 + ooff, ld, HID_DIM, by * 64, bx * 64, threadIdx.x);
  } else if (bid < 10240) {
    int b = bid - 6144;
    tr64_body(wo, woT, HID_DIM, HID_DIM, (b >> 6) * 64, (b & 63) * 64, threadIdx.x);
  } else {
    long i = (long)(bid - 10240) * 256 + threadIdx.x;
    float4 v = ((const float4*)hs)[i];
    ushort4 o;
    o.x = f2bf(v.x); o.y = f2bf(v.y); o.z = f2bf(v.z); o.w = f2bf(v.w);
    ((ushort4*)hsb)[i] = o;
  }
}

// merged mid v2: qnrope (bid<20480; 4 (s,head) pairs per 256-thr block) +
// V^T per kv head (20480..20991) + mem^T (20992..21023) + norm copy (21024..21535)
__global__ void k_mid2(const u16* __restrict__ qkvb, const int* __restrict__ pos,
                       u16* __restrict__ qnb, u16* __restrict__ qrb,
                       u16* __restrict__ knb, u16* __restrict__ krb,
                       u16* __restrict__ vtb, const float* __restrict__ memf,
                       const float* __restrict__ norm, u16* __restrict__ bc) {
  int bid = blockIdx.x;
  if (bid < 20480) {
    int p = bid * 4 + (threadIdx.x >> 6);   // (s,y) pair index, [0, 81920)
    int s = p & (S_LEN - 1), y = p >> 11;
    int l = threadIdx.x & 63;
    bool isq = y < NH;
    int h = isq ? y : y - NH;
    const u16* row = qkvb + (long)s * QKV_N + (isq ? h * HD : HID_DIM + h * HD);
    float x0 = bf2f(row[l]), x1 = bf2f(row[l + 64]);
    float f0 = x0 > 0.f ? x0 + 1.f : __expf(x0);
    float f1 = x1 > 0.f ? x1 + 1.f : __expf(x1);
    float sum = f0 + f1;
#pragma unroll
    for (int m = 32; m >= 1; m >>= 1) sum += __shfl_xor(sum, m);
    float inv = 1.f / (sum + 1e-8f);
    float y0 = f0 * inv, y1 = f1 * inv;
    long o = ((long)h * S_LEN + s) * HD;
    float pp = (float)pos[s];
    float ang = pp * expf(-(float)l * (9.210340371976184f / 64.0f));
    float c = cosf(ang), sn = sinf(ang);
    u16 r0 = f2bf(x0 * c - x1 * sn), r1 = f2bf(x1 * c + x0 * sn);
    if (isq) {
      qnb[o + l] = f2bf(y0); qnb[o + l + 64] = f2bf(y1);
      qrb[o + l] = r0; qrb[o + l + 64] = r1;
    } else {
      knb[o + l] = f2bf(y0); knb[o + l + 64] = f2bf(y1);
      krb[o + l] = r0; krb[o + l + 64] = r1;
    }
  } else if (bid < 20992) {
    int b = bid - 20480;
    int z = b >> 6, sub = b & 63;
    int bx = sub & 1, by = sub >> 1;
    tr64u_body(qkvb + HID_DIM + NKV * HD + z * HD, vtb + (long)z * HD * S_LEN,
               QKV_N, S_LEN, by * 64, bx * 64, threadIdx.x);
  } else if (bid < 21024) {
    int b = bid - 20992;
    int h = b >> 2, sub = b & 3;
    tr64_body(memf + (long)h * HD * HD, bc + (long)h * 32768,
              HD, HD, (sub >> 1) * 64, (sub & 1) * 64, threadIdx.x);
  } else {
    int cid = bid - 21024;
    int h = cid >> 6, chunk = cid & 63;
    int i = chunk * 256 + threadIdx.x;
    bc[(long)h * 32768 + 16384 + i] = f2bf(norm[(long)h * 16384 + i]);
  }
}

// ---------------- GEMM v9: 8-phase 256xBN, BK=64, A depth ATRI ----------------
// ATRI=2 is the round-7-proven schedule (all call sites use it).

template <int BN, int ATRI>
__global__ __launch_bounds__(512, 2) void k_gemm8(
    const u16* __restrict__ A, const u16* __restrict__ A2, int zsplit,
    const u16* __restrict__ Bt, void* __restrict__ Cv,
    int kloop, int lda, int ldb, int ldc,
    long strideA, long strideB, long strideC, int bmodB, int obf) {
  constexpr int NBG = BN / 64;
  constexpr int NNI = BN / 64;
  constexpr int AHEAD = ATRI - 1;
  constexpr int WAITN = NBG + 4 * (AHEAD - 1);
  constexpr int AELT = 16384;
  constexpr int ABYTES = ATRI * AELT;
  constexpr int BN64 = BN * 64;
  __shared__ __align__(16) u16 lds[ABYTES + 2 * BN64];
  const int bz = blockIdx.z;
  const u16* Ap = (bz < zsplit) ? (A + (long)bz * strideA)
                                : (A2 + (long)(bz - zsplit) * strideA);
  const u16* Bp = Bt + (long)(bz % bmodB) * strideB;
  const long coff = (long)bz * strideC;

  const int gx = gridDim.x, gy = gridDim.y;
  const int nwg = gx * gy;
  int id = blockIdx.y * gx + blockIdx.x;
  if (!(nwg & 7)) { int q = nwg >> 3; id = (id & 7) * q + (id >> 3); }
  const int m0 = (id % gy) * 256;
  const int n0 = (id / gy) * BN;

  const int tid = threadIdx.x, wid = tid >> 6, lane = tid & 63;
  const int l15 = lane & 15, lhi = lane >> 4;
  const int wm = wid >> 2, wn = wid & 3;

  const int srow = (wid << 3) + (lane >> 3);
  const int ssw = ((lane & 7) ^ (lane >> 3)) * 8;
  auto stA = [&](int ab, int g, long kt) {
    gl_lds16(Ap + (long)(m0 + g * 64 + srow) * lda + kt + ssw,
             &lds[ab * AELT + (g * 64 + (wid << 3)) * 64]);
  };
  auto stB = [&](int d, int g, long kt) {
    gl_lds16(Bp + (long)(n0 + g * 64 + srow) * ldb + kt + ssw,
             &lds[ABYTES + d * BN64 + (g * 64 + (wid << 3)) * 64]);
  };

  const int swb = l15 & 7;
  const int aBase = (wm * 128 + l15) * 64;
  const int bBase = (wn * (BN / 4) + l15) * 64;
  const int ko0 = (lhi ^ swb) * 8;
  const int ko1 = ((4 + lhi) ^ swb) * 8;

  const int KT = kloop >> 6;
  const int NIT = KT >> 1;

  f32x4 acc[8][NNI];
#pragma unroll
  for (int i = 0; i < 8; i++)
#pragma unroll
    for (int j = 0; j < NNI; j++) acc[i][j] = (f32x4){0.f, 0.f, 0.f, 0.f};

#pragma unroll
  for (int g = 0; g < 4; g++) stA(0, g, 0);
#pragma unroll
  for (int g = 0; g < NBG; g++) stB(0, g, 0);
  if (ATRI > 2) {
#pragma unroll
    for (int g = 0; g < 4; g++) stA(1, g, 64);
  }
#pragma unroll
  for (int g = 0; g < NBG; g++) stB(1, g, 64);
  asm volatile("s_waitcnt vmcnt(%0)" :: "i"(WAITN) : "memory");
  __builtin_amdgcn_s_barrier();
  asm volatile("" ::: "memory");

  int ab0 = 0;
  for (int t = 0; t < NIT; ++t) {
    const int uS0 = 2 * t + AHEAD;
    const int uS1 = 2 * t + 1 + AHEAD;
    const int abR0 = ab0;
    const int abR1 = (ab0 + 1 < ATRI) ? (ab0 + 1) : 0;
    const int abS0 = (ab0 + AHEAD < ATRI) ? (ab0 + AHEAD) : (ab0 + AHEAD - ATRI);
    const int abS1 = (abS0 + 1 < ATRI) ? (abS0 + 1) : 0;
    const long kA0 = (long)uS0 * 64, kA1 = (long)uS1 * 64;
    const long kB0 = (long)(2 * t + 2) * 64;
    const long kB1 = (long)(2 * t + 3) * 64;
    const bool sA0 = uS0 < KT, sA1 = uS1 < KT;
    const bool sB0 = (2 * t + 2) < KT, sB1 = (2 * t + 3) < KT;
    const bool last = (t + 1 == NIT);

    {
      const u16* la = &lds[abR0 * AELT];
      const u16* lbB = &lds[ABYTES];
      bf16x8 Bf[NNI][2];
#pragma unroll
      for (int p = 0; p < 4; p++) {
        if (p == 0) {
#pragma unroll
          for (int ni = 0; ni < NNI; ni++) {
            Bf[ni][0] = *(const bf16x8*)&lbB[bBase + ni * 1024 + ko0];
            Bf[ni][1] = *(const bf16x8*)&lbB[bBase + ni * 1024 + ko1];
          }
        }
        bf16x8 a0k0 = *(const bf16x8*)&la[aBase + (2 * p) * 1024 + ko0];
        bf16x8 a0k1 = *(const bf16x8*)&la[aBase + (2 * p) * 1024 + ko1];
        bf16x8 a1k0 = *(const bf16x8*)&la[aBase + (2 * p + 1) * 1024 + ko0];
        bf16x8 a1k1 = *(const bf16x8*)&la[aBase + (2 * p + 1) * 1024 + ko1];
        if (p == 0) { if (sA0) { stA(abS0, 0, kA0); stA(abS0, 1, kA0); } }
        else if (p == 1) { if (sA0) { stA(abS0, 2, kA0); stA(abS0, 3, kA0); } }
        else if (p == 2) { if (sB0) { stB(0, 0, kB0); stB(0, 1, kB0); } }
        else {
          if (sB0) { stB(0, 2, kB0); if (NBG > 3) stB(0, 3, kB0); }
        }
        asm volatile("" ::: "memory");
        if (p == 3) {
          if (last) asm volatile("s_waitcnt vmcnt(0)" ::: "memory");
          else      asm volatile("s_waitcnt vmcnt(%0)" :: "i"(WAITN) : "memory");
        }
        __builtin_amdgcn_s_barrier();
        asm volatile("" ::: "memory");
        __builtin_amdgcn_s_setprio(1);
#pragma unroll
        for (int ni = 0; ni < NNI; ni++) {
          acc[2 * p][ni] = __builtin_amdgcn_mfma_f32_16x16x32_bf16(a0k0, Bf[ni][0], acc[2 * p][ni], 0, 0, 0);
          acc[2 * p][ni] = __builtin_amdgcn_mfma_f32_16x16x32_bf16(a0k1, Bf[ni][1], acc[2 * p][ni], 0, 0, 0);
          acc[2 * p + 1][ni] = __builtin_amdgcn_mfma_f32_16x16x32_bf16(a1k0, Bf[ni][0], acc[2 * p + 1][ni], 0, 0, 0);
          acc[2 * p + 1][ni] = __builtin_amdgcn_mfma_f32_16x16x32_bf16(a1k1, Bf[ni][1], acc[2 * p + 1][ni], 0, 0, 0);
        }
        __builtin_amdgcn_s_setprio(0);
        asm volatile("" ::: "memory");
        __builtin_amdgcn_s_barrier();
        asm volatile("" ::: "memory");
      }
    }
    {
      const u16* la = &lds[abR1 * AELT];
      const u16* lbB = &lds[ABYTES + BN64];
      bf16x8 Bf[NNI][2];
#pragma unroll
      for (int p = 0; p < 4; p++) {
        if (p == 0) {
#pragma unroll
          for (int ni = 0; ni < NNI; ni++) {
            Bf[ni][0] = *(const bf16x8*)&lbB[bBase + ni * 1024 + ko0];
            Bf[ni][1] = *(const bf16x8*)&lbB[bBase + ni * 1024 + ko1];
          }
        }
        bf16x8 a0k0 = *(const bf16x8*)&la[aBase + (2 * p) * 1024 + ko0];
        bf16x8 a0k1 = *(const bf16x8*)&la[aBase + (2 * p) * 1024 + ko1];
        bf16x8 a1k0 = *(const bf16x8*)&la[aBase + (2 * p + 1) * 1024 + ko0];
        bf16x8 a1k1 = *(const bf16x8*)&la[aBase + (2 * p + 1) * 1024 + ko1];
        if (p == 0) { if (sA1) { stA(abS1, 0, kA1); stA(abS1, 1, kA1); } }
        else if (p == 1) { if (sA1) { stA(abS1, 2, kA1); stA(abS1, 3, kA1); } }
        else if (p == 2) { if (sB1) { stB(1, 0, kB1); stB(1, 1, kB1); } }
        else {
          if (sB1) { stB(1, 2, kB1); if (NBG > 3) stB(1, 3, kB1); }
        }
        asm volatile("" ::: "memory");
        if (p == 3 && !last)
          asm volatile("s_waitcnt vmcnt(%0)" :: "i"(WAITN) : "memory");
        __builtin_amdgcn_s_barrier();
        asm volatile("" ::: "memory");
        __builtin_amdgcn_s_setprio(1);
#pragma unroll
        for (int ni = 0; ni < NNI; ni++) {
          acc[2 * p][ni] = __builtin_amdgcn_mfma_f32_16x16x32_bf16(a0k0, Bf[ni][0], acc[2 * p][ni], 0, 0, 0);
          acc[2 * p][ni] = __builtin_amdgcn_mfma_f32_16x16x32_bf16(a0k1, Bf[ni][1], acc[2 * p][ni], 0, 0, 0);
          acc[2 * p + 1][ni] = __builtin_amdgcn_mfma_f32_16x16x32_bf16(a1k0, Bf[ni][0], acc[2 * p + 1][ni], 0, 0, 0);
          acc[2 * p + 1][ni] = __builtin_amdgcn_mfma_f32_16x16x32_bf16(a1k1, Bf[ni][1], acc[2 * p + 1][ni], 0, 0, 0);
        }
        __builtin_amdgcn_s_setprio(0);
        asm volatile("" ::: "memory");
        __builtin_amdgcn_s_barrier();
        asm volatile("" ::: "memory");
      }
    }
    ab0 = (ab0 + 2 < ATRI) ? (ab0 + 2) : (ab0 + 2 - ATRI);
  }

#pragma unroll
  for (int mi = 0; mi < 8; mi++)
#pragma unroll
    for (int ni = 0; ni < NNI; ni++)
#pragma unroll
      for (int j = 0; j < 4; j++) {
        long row = m0 + wm * 128 + mi * 16 + lhi * 4 + j;
        long col = n0 + wn * (BN / 4) + ni * 16 + l15;
        if (obf)
          ((u16*)Cv)[coff + row * ldc + col] = f2bf(acc[mi][ni][j]);
        else
          ((float*)Cv)[coff + row * ldc + col] = acc[mi][ni][j];
      }
}

// ---------------- split-K add epilogue ----------------

__global__ void k_addp(const u16* __restrict__ p0, const u16* __restrict__ p1,
                       float* __restrict__ out) {
  long i = ((long)blockIdx.x * 256 + threadIdx.x) * 8;
  ushort4 a0 = *(const ushort4*)&p0[i], a1 = *(const ushort4*)&p0[i + 4];
  ushort4 b0 = *(const ushort4*)&p1[i], b1 = *(const ushort4*)&p1[i + 4];
  float4 o0, o1;
  o0.x = bf2f(a0.x) + bf2f(b0.x); o0.y = bf2f(a0.y) + bf2f(b0.y);
  o0.z = bf2f(a0.z) + bf2f(b0.z); o0.w = bf2f(a0.w) + bf2f(b0.w);
  o1.x = bf2f(a1.x) + bf2f(b1.x); o1.y = bf2f(a1.y) + bf2f(b1.y);
  o1.z = bf2f(a1.z) + bf2f(b1.z); o1.w = bf2f(a1.w) + bf2f(b1.w);
  *(float4*)&out[i] = o0;
  *(float4*)&out[i + 4] = o1;
}

// ---------------- flash attention v4: fused combine epilogue ----------------

__global__ __launch_bounds__(256, 2) void k_flash4(
    const u16* __restrict__ qr, const u16* __restrict__ kr,
    const u16* __restrict__ vt, const u16* __restrict__ rawq,
    const float* __restrict__ beta, u16* __restrict__ comb) {
  __shared__ u16 KV[2][16384];
  __shared__ u16 Ps[4][16 * 64];
  const int bx = blockIdx.x, h = blockIdx.y;
  const int hk = h >> 2;
  const int tid = threadIdx.x, wid = tid >> 6, lane = tid & 63;
  const int l15 = lane & 15, lhi = lane >> 4;
  const u16* qbase = qr + (long)h * S_LEN * HD;
  const u16* kb0 = kr + (long)hk * S_LEN * HD;
  const u16* vb0 = vt + (long)hk * HD * S_LEN;
  u16* P = Ps[wid];
  const float g = 1.f / (1.f + __expf(-beta[0]));

  int kr_r[4], kr_sc[4], vr_r[4], vr_sc[4];
#pragma unroll
  for (int it = 0; it < 4; it++) {
    int chunk = it * 4 + wid;
    kr_r[it] = chunk * 4 + (lane >> 4);
    kr_sc[it] = ((lane & 15) * 8) ^ ((kr_r[it] & 7) * 8);
    vr_r[it] = chunk * 8 + (lane >> 3);
    vr_sc[it] = ((lane & 7) * 8) ^ ((vr_r[it] & 7) * 8);
  }

  for (int si = 0; si < 2; si++) {
    const int s = si ? (31 - bx) : bx;
    const int qs = s * 64 + wid * 16;
    bf16x8 aq[4];
#pragma unroll
    for (int kc = 0; kc < 4; kc++)
      aq[kc] = *(const bf16x8*)&qbase[(long)(qs + l15) * HD + kc * 32 + lhi * 8];
    f32x4 accO[8];
#pragma unroll
    for (int i = 0; i < 8; i++) accO[i] = (f32x4){0.f, 0.f, 0.f, 0.f};
    float rs[4] = {0.f, 0.f, 0.f, 0.f};

    if (si) __syncthreads();
    {
      u16* Kb = KV[0];
#pragma unroll
      for (int it = 0; it < 4; it++)
        gl_lds16(kb0 + (long)kr_r[it] * HD + kr_sc[it], &Kb[(it * 4 + wid) * 512]);
#pragma unroll
      for (int it = 0; it < 4; it++)
        gl_lds16(vb0 + (long)vr_r[it] * S_LEN + vr_sc[it], &Kb[8192 + (it * 4 + wid) * 512]);
    }
    int cur = 0;

    for (int t = 0; t <= s; t++) {
      asm volatile("s_waitcnt vmcnt(0)" ::: "memory");
      __syncthreads();
      if (t < s) {
        u16* Kb = KV[cur ^ 1];
        const long kt = (long)(t + 1) * 64;
#pragma unroll
        for (int it = 0; it < 4; it++)
          gl_lds16(kb0 + (kt + kr_r[it]) * HD + kr_sc[it], &Kb[(it * 4 + wid) * 512]);
#pragma unroll
        for (int it = 0; it < 4; it++)
          gl_lds16(vb0 + (long)vr_r[it] * S_LEN + kt + vr_sc[it], &Kb[8192 + (it * 4 + wid) * 512]);
      }
      const u16* Ks = KV[cur];
      const u16* Vs = Ks + 8192;

      f32x4 accS[4];
#pragma unroll
      for (int i = 0; i < 4; i++) accS[i] = (f32x4){0.f, 0.f, 0.f, 0.f};
#pragma unroll
      for (int ni = 0; ni < 4; ni++) {
        int row = ni * 16 + l15;
#pragma unroll
        for (int kc = 0; kc < 4; kc++) {
          bf16x8 bk = *(const bf16x8*)&Ks[row * 128 + ((kc * 32 + lhi * 8) ^ ((row & 7) * 8))];
          accS[ni] = __builtin_amdgcn_mfma_f32_16x16x32_bf16(aq[kc], bk, accS[ni], 0, 0, 0);
        }
      }
      const bool diag = (t == s);
#pragma unroll
      for (int ni = 0; ni < 4; ni++) {
        int col = t * 64 + ni * 16 + l15;
#pragma unroll
        for (int j = 0; j < 4; j++) {
          int row = qs + lhi * 4 + j;
          float p = (!diag || col <= row) ? __expf(accS[ni][j] * SCALE_F) : 0.f;
          rs[j] += p;
          int pr = lhi * 4 + j;
          P[pr * 64 + ((ni * 16 + l15) ^ ((pr & 7) * 8))] = f2bf(p);
        }
      }
      asm volatile("s_waitcnt lgkmcnt(0)" ::: "memory");
      __builtin_amdgcn_sched_barrier(0);
      bf16x8 ap[2];
#pragma unroll
      for (int ks = 0; ks < 2; ks++)
        ap[ks] = *(const bf16x8*)&P[l15 * 64 + ((ks * 32 + lhi * 8) ^ ((l15 & 7) * 8))];
#pragma unroll
      for (int nj = 0; nj < 8; nj++) {
        int row = nj * 16 + l15;
#pragma unroll
        for (int ks = 0; ks < 2; ks++) {
          bf16x8 bv = *(const bf16x8*)&Vs[row * 64 + ((ks * 32 + lhi * 8) ^ ((row & 7) * 8))];
          accO[nj] = __builtin_amdgcn_mfma_f32_16x16x32_bf16(ap[ks], bv, accO[nj], 0, 0, 0);
        }
      }
      cur ^= 1;
    }
#pragma unroll
    for (int j = 0; j < 4; j++) {
      float v = rs[j];
      v += __shfl_xor(v, 1);
      v += __shfl_xor(v, 2);
      v += __shfl_xor(v, 4);
      v += __shfl_xor(v, 8);
      rs[j] = 1.f / v;
    }
#pragma unroll
    for (int nj = 0; nj < 8; nj++)
#pragma unroll
      for (int j = 0; j < 4; j++) {
        int row = qs + lhi * 4 + j;
        int col = nj * 16 + l15;
        long rb = ((long)h * S_LEN + row) * 256 + col;
        float mo = bf2f(rawq[rb]) / (bf2f(rawq[rb + 128]) + 1e-8f);
        float ao = accO[nj][j] * rs[j];
        comb[(long)row * HID_DIM + h * HD + col] = f2bf(g * mo + (1.f - g) * ao);
      }
  }
}

// ---------------- delta v4: uvret fused into LDS staging + norm colsum ----------------

__global__ __launch_bounds__(256) void k_delta_part(
    const u16* __restrict__ knb, const u16* __restrict__ rawk,
    const u16* __restrict__ qkvb,
    float* __restrict__ dpart, float* __restrict__ npart) {
  __shared__ float knc[64][128];
  __shared__ u16 Uc[64][128];
  const int h = blockIdx.x, c = blockIdx.y, t = threadIdx.x;
  const long rb = ((long)h * S_LEN + (long)c * 64) * HD;
  const long rkb = ((long)h * S_LEN + (long)c * 64) * 256;
  const u16* vb = qkvb + HID_DIM + NKV * HD + h * HD + (long)c * 64 * QKV_N;
  for (int i = t; i < 1024; i += 256) {
    int r = i >> 4, cb = (i & 15) * 8;
    ushort4 k0 = *(const ushort4*)&knb[rb + (long)r * HD + cb];
    ushort4 k1 = *(const ushort4*)&knb[rb + (long)r * HD + cb + 4];
    knc[r][cb + 0] = bf2f(k0.x); knc[r][cb + 1] = bf2f(k0.y);
    knc[r][cb + 2] = bf2f(k0.z); knc[r][cb + 3] = bf2f(k0.w);
    knc[r][cb + 4] = bf2f(k1.x); knc[r][cb + 5] = bf2f(k1.y);
    knc[r][cb + 6] = bf2f(k1.z); knc[r][cb + 7] = bf2f(k1.w);
    ushort4 n0 = *(const ushort4*)&rawk[rkb + (long)r * 256 + cb];
    ushort4 n1 = *(const ushort4*)&rawk[rkb + (long)r * 256 + cb + 4];
    ushort4 dn0 = *(const ushort4*)&rawk[rkb + (long)r * 256 + 128 + cb];
    ushort4 dn1 = *(const ushort4*)&rawk[rkb + (long)r * 256 + 128 + cb + 4];
    ushort4 v0 = *(const ushort4*)&vb[(long)r * QKV_N + cb];
    ushort4 v1 = *(const ushort4*)&vb[(long)r * QKV_N + cb + 4];
    ushort4 u0, u1;
    u0.x = f2bf(bf2f(v0.x) - bf2f(n0.x) / (bf2f(dn0.x) + 1e-8f));
    u0.y = f2bf(bf2f(v0.y) - bf2f(n0.y) / (bf2f(dn0.y) + 1e-8f));
    u0.z = f2bf(bf2f(v0.z) - bf2f(n0.z) / (bf2f(dn0.z) + 1e-8f));
    u0.w = f2bf(bf2f(v0.w) - bf2f(n0.w) / (bf2f(dn0.w) + 1e-8f));
    u1.x = f2bf(bf2f(v1.x) - bf2f(n1.x) / (bf2f(dn1.x) + 1e-8f));
    u1.y = f2bf(bf2f(v1.y) - bf2f(n1.y) / (bf2f(dn1.y) + 1e-8f));
    u1.z = f2bf(bf2f(v1.z) - bf2f(n1.z) / (bf2f(dn1.z) + 1e-8f));
    u1.w = f2bf(bf2f(v1.w) - bf2f(n1.w) / (bf2f(dn1.w) + 1e-8f));
    *(ushort4*)&Uc[r][cb] = u0;
    *(ushort4*)&Uc[r][cb + 4] = u1;
  }
  __syncthreads();

  const int e = t & 127, dh = (t >> 7) * 64;
  float acc[64];
#pragma unroll
  for (int d = 0; d < 64; d++) acc[d] = 0.f;
  for (int s = 0; s < 64; s++) {
    float u = bf2f(Uc[s][e]);
#pragma unroll
    for (int dq = 0; dq < 16; dq++) {
      float4 k4 = *(const float4*)&knc[s][dh + dq * 4];
      acc[dq * 4 + 0] += k4.x * u;
      acc[dq * 4 + 1] += k4.y * u;
      acc[dq * 4 + 2] += k4.z * u;
      acc[dq * 4 + 3] += k4.w * u;
    }
  }
  long ob = (((long)c * NKV + h) * 128 + dh) * 128 + e;
#pragma unroll
  for (int d = 0; d < 64; d++) dpart[ob + (long)d * 128] = acc[d];

  {
    int j = e, half = t >> 7;
    float cs = 0.f;
#pragma unroll
    for (int s = 0; s < 32; s++) cs += knc[half * 32 + s][j];
    npart[(((long)c * 2 + half) * NKV + h) * 128 + j] = cs;
  }
}

// merged delta_reduce (bid<512) + norm_write (bid>=512)
__global__ void k_finish(const float* __restrict__ dpart, const float* __restrict__ npart,
                         const float* __restrict__ mem, const float* __restrict__ norm,
                         float* __restrict__ outmem, float* __restrict__ outn) {
  int bid = blockIdx.x;
  if (bid < 512) {
    long i = (long)bid * 256 + threadIdx.x;
    const long N = (long)NKV * HD * HD;
    float a = 0.f;
#pragma unroll 8
    for (int c = 0; c < 32; c++) a += dpart[(long)c * N + i];
    outmem[i] = mem[i] + a;
  } else {
    int b2 = bid - 512;
    int h = b2 >> 6, y = b2 & 63;
    int j = threadIdx.x & 127;
    int r = y * 2 + (threadIdx.x >> 7);
    float cs = 0.f;
#pragma unroll 8
    for (int cc = 0; cc < 64; cc++) cs += npart[((long)cc * NKV + h) * 128 + j];
    long o = (long)h * HD * HD + (long)r * HD + j;
    outn[o] = norm[o] + cs;
  }
}

// ---------------- host ----------------
// Phase order: A (prep incl wo^T->d_out scratch + QKV), M (mid2: qnrope+vtb+bc),
// F (retrieval), H (flash+combine), K (delta/finish), J (out-proj + addp).
// 9 dispatches. woT in d_out[0,32MB) — dead until addp overwrites with final out.

extern "C" void kernel_launch(void* const* d_in, const int* in_sizes, int n_in,
                              void* d_out, int out_size, void* d_ws, size_t ws_size,
                              hipStream_t stream) {
  const float* hs = (const float*)d_in[0];
  const int* pos = (const int*)d_in[1];
  const float* wq = (const float*)d_in[2];
  const float* wk = (const float*)d_in[3];
  const float* wv = (const float*)d_in[4];
  const float* wo = (const float*)d_in[5];
  const float* memf = (const float*)d_in[6];
  const float* normf = (const float*)d_in[7];
  const float* beta = (const float*)d_in[8];
  (void)in_sizes; (void)n_in; (void)out_size; (void)ws_size;

  float* out = (float*)d_out;
  float* out_mem = out + (long)S_LEN * HID_DIM;
  float* out_norm = out_mem + NKV * HD * HD;
  u16* woT = (u16*)d_out;  // scratch over out[0,32MB), consumed before addp

  const size_t MB = 1u << 20;
  char* w = (char*)d_ws;
  u16* hsb    = (u16*)(w + 0);
  u16* qnb    = (u16*)(w + 0);
  u16* comb   = (u16*)(w + 0);
  u16* wT6    = (u16*)(w + 16 * MB);
  u16* rawq   = (u16*)(w + 16 * MB);
  u16* rawk   = (u16*)(w + 48 * MB);
  u16* bc     = (u16*)(w + 57 * MB);
  u16* vtb    = (u16*)(w + 57 * MB + 512 * 1024);
  u16* qkvb   = (u16*)(w + 66 * MB + 512 * 1024);
  u16* p0     = (u16*)(w + 90 * MB + 512 * 1024);
  u16* qrb    = (u16*)(w + 130 * MB + 512 * 1024);
  float* dpart= (float*)(w + 130 * MB + 512 * 1024);
  u16* p1     = (u16*)(w + 130 * MB + 512 * 1024);
  u16* krb    = (u16*)(w + 146 * MB + 512 * 1024);
  float* npart= (float*)(w + 146 * MB + 512 * 1024);
  u16* knb    = (u16*)(w + 150 * MB + 512 * 1024);

  // --- A: merged prep (hs conv + all 4 weight transposes) + QKV projection ---
  k_prep<<<dim3(18432), dim3(256), 0, stream>>>(hs, hsb, wq, wk, wv, wT6, wo, woT);
  k_gemm8<192, 2><<<dim3(QKV_N / 192, S_LEN / 256, 1), dim3(512), 0, stream>>>(
      hsb, hsb, 1 << 30, wT6, qkvb, HID_DIM, HID_DIM, HID_DIM, QKV_N,
      0L, 0L, 0L, 1, 1);

  // --- M: merged mid2 (qnrope + V^T + mem^T + norm copy) ---
  k_mid2<<<dim3(21536), dim3(256), 0, stream>>>(
      qkvb, pos, qnb, qrb, knb, krb, vtb, memf, normf, bc);

  // --- F: retrieval raws, q+k merged into one dispatch (z = 40) ---
  k_gemm8<256, 2><<<dim3(1, 8, NH + NKV), dim3(512), 0, stream>>>(
      qnb, knb, NH, bc, rawq, HD, HD, HD, 256,
      (long)(S_LEN * HD), (long)(256 * HD), (long)(S_LEN * 256), NKV, 1);

  // --- H: attention with fused combine (reads rawq) ---
  k_flash4<<<dim3(16, NH), dim3(256), 0, stream>>>(qrb, krb, vtb, rawq, beta, comb);

  // --- K: memory / norm updates (reads qkvb v-cols + rawk) ---
  k_delta_part<<<dim3(NKV, 32), dim3(256), 0, stream>>>(knb, rawk, qkvb, dpart, npart);
  k_finish<<<dim3(1024), dim3(256), 0, stream>>>(dpart, npart, memf, normf, out_mem, out_norm);

  // --- J: output projection (split-K2, bf16 partials + add; reads woT from d_out) ---
  k_gemm8<256, 2><<<dim3(HID_DIM / 256, S_LEN / 256, 2), dim3(512), 0, stream>>>(
      comb, comb, 1 << 30, woT, p0, 2048, HID_DIM, HID_DIM, HID_DIM,
      2048L, 2048L, (long)(p1 - p0), 2, 1);
  k_addp<<<dim3(S_LEN * HID_DIM / 2048), dim3(256), 0, stream>>>(p0, p1, out);
}